// Round 4
// baseline (403.674 us; speedup 1.0000x reference)
//
#include <hip/hip_runtime.h>

typedef unsigned short u16;
typedef __attribute__((ext_vector_type(8))) short short8;
typedef __attribute__((ext_vector_type(4))) float f32x4;

#define AS1C(p) ((const __attribute__((address_space(1))) void*)(p))
#define AS3(p)  ((__attribute__((address_space(3))) void*)(p))

constexpr int CC    = 256;      // channels
constexpr int HWSZ  = 4096;     // H*W
constexpr int NNODE = 131072;   // B*H*W
constexpr int EEDG  = 524288;   // edges
constexpr int CAP   = 32;       // per-node bucket capacity

__device__ __forceinline__ float bf2f(u16 h){ unsigned u = ((unsigned)h)<<16; float f; __builtin_memcpy(&f,&u,4); return f; }
__device__ __forceinline__ u16 f2bf(float f){ unsigned u; __builtin_memcpy(&u,&f,4); return (u16)((u + 0x7FFFu + ((u>>16)&1u))>>16); }
__device__ __forceinline__ float gelu_exact(float v){ return 0.5f*v*(1.0f + erff(v*0.7071067811865476f)); }

__device__ __forceinline__ void unpack8(uint4 q, float f[8]){
  unsigned w0=q.x,w1=q.y,w2=q.z,w3=q.w;
  unsigned l0=w0<<16, h0=w0&0xffff0000u, l1=w1<<16, h1=w1&0xffff0000u;
  unsigned l2=w2<<16, h2=w2&0xffff0000u, l3=w3<<16, h3=w3&0xffff0000u;
  __builtin_memcpy(&f[0],&l0,4); __builtin_memcpy(&f[1],&h0,4);
  __builtin_memcpy(&f[2],&l1,4); __builtin_memcpy(&f[3],&h1,4);
  __builtin_memcpy(&f[4],&l2,4); __builtin_memcpy(&f[5],&h2,4);
  __builtin_memcpy(&f[6],&l3,4); __builtin_memcpy(&f[7],&h3,4);
}

// ---------------- fp32 64x64 tiled transpose + bf16 hi/lo split ----------------
__global__ __launch_bounds__(256) void transpose_split(const float* __restrict__ src,
                                                       u16* __restrict__ dhi, u16* __restrict__ dlo,
                                                       int R, int Ccols, size_t sb_in, size_t sb_out)
{
  __shared__ float t[64][65];
  const float* s = src + blockIdx.z*sb_in + (size_t)(blockIdx.y*64)*Ccols + blockIdx.x*64;
  size_t obase   = blockIdx.z*sb_out + (size_t)(blockIdx.x*64)*R + blockIdx.y*64;
  int tid = threadIdx.x;
  for (int i=0;i<4;++i){
    int idx = i*256 + tid;
    int r = idx>>4, q = idx&15;
    float4 v = *(const float4*)(s + (size_t)r*Ccols + q*4);
    t[r][q*4+0]=v.x; t[r][q*4+1]=v.y; t[r][q*4+2]=v.z; t[r][q*4+3]=v.w;
  }
  __syncthreads();
  for (int i=0;i<2;++i){
    int idx = i*256 + tid;
    int rr = idx>>3, ch = idx&7;
    u16 hi[8], lo[8];
    for (int j=0;j<8;++j){
      float f = t[ch*8+j][rr];
      u16 h = f2bf(f); hi[j] = h;
      lo[j] = f2bf(f - bf2f(h));
    }
    *(uint4*)(dhi + obase + (size_t)rr*R + ch*8) = *(uint4*)hi;
    if (dlo) *(uint4*)(dlo + obase + (size_t)rr*R + ch*8) = *(uint4*)lo;
  }
}

// ---------------- row-major fp32 -> bf16 hi/lo split (no transpose; for Wp) ----------------
__global__ __launch_bounds__(256) void split_rm(const float* __restrict__ src,
                                                u16* __restrict__ dhi, u16* __restrict__ dlo)
{
  int i = blockIdx.x*256 + threadIdx.x;           // one float4 per thread
  float4 v = ((const float4*)src)[i];
  float f[4] = {v.x,v.y,v.z,v.w};
  ushort4 h, l;
  u16 t;
  t = f2bf(f[0]); h.x = t; l.x = f2bf(f[0]-bf2f(t));
  t = f2bf(f[1]); h.y = t; l.y = f2bf(f[1]-bf2f(t));
  t = f2bf(f[2]); h.z = t; l.z = f2bf(f[2]-bf2f(t));
  t = f2bf(f[3]); h.w = t; l.w = f2bf(f[3]-bf2f(t));
  ((ushort4*)dhi)[i] = h;
  ((ushort4*)dlo)[i] = l;
}

// ---------------- bias2[n] = sum_k bp[k] * Wg[k,n] ----------------
__global__ void bias2_k(const float* __restrict__ bp, const float* __restrict__ Wg,
                        float* __restrict__ b2)
{
  int n = threadIdx.x;
  float s = 0.f;
  for (int k=0;k<256;++k) s += bp[k]*Wg[(size_t)k*256 + n];
  b2[n] = s;
}

// ---------------- split-precision GEMM (kept for W2T = WgT @ Wp precompute) ----------------
__global__ __launch_bounds__(256) void gemm_split(const u16* __restrict__ Ahi, const u16* __restrict__ Alo,
                                                  const u16* __restrict__ Bhi, const u16* __restrict__ Blo,
                                                  const float* __restrict__ bias,
                                                  u16* __restrict__ Chi, u16* __restrict__ Clo)
{
  __shared__ u16 As_hi[128*32];
  __shared__ u16 As_lo[128*32];
  __shared__ u16 Bs_hi[128*32];
  __shared__ u16 Bs_lo[128*32];
  const int tid  = threadIdx.x;
  const int wid  = tid>>6, lane = tid&63;
  const int row0 = blockIdx.x*128;
  const int col0 = blockIdx.y*128;
  const int gk = lane>>4, ml = lane&15;
  const int wm = wid>>1, wn = wid&1;

  f32x4 acc[4][4];
  for (int i=0;i<4;++i) for (int j=0;j<4;++j) for (int e=0;e<4;++e) acc[i][j][e]=0.f;

  for (int kt=0; kt<256; kt+=32) {
#define STAGE(G, S, rbase)                                                            \
    for (int it=0; it<2; ++it) {                                                      \
      int qb = (it*4+wid)*64;                                                         \
      int qq = qb + lane;                                                             \
      int m  = qq>>2, sc = qq&3;                                                      \
      int gs = sc ^ ((m>>1)&3);                                                       \
      __builtin_amdgcn_global_load_lds(AS1C(G + (size_t)((rbase)+m)*256 + kt + gs*8), \
                                       AS3(S + (size_t)qb*8), 16, 0, 0);              \
    }
    STAGE(Ahi, As_hi, row0)
    STAGE(Alo, As_lo, row0)
    STAGE(Bhi, Bs_hi, col0)
    STAGE(Blo, Bs_lo, col0)
#undef STAGE
    asm volatile("s_waitcnt vmcnt(0)" ::: "memory");
    __syncthreads();

    short8 ah[4], al[4], bh[4], bl[4];
    for (int f=0; f<4; ++f) {
      int m  = wm*64 + f*16 + ml;
      int sa = gk ^ ((m>>1)&3);
      ah[f] = *(const short8*)&As_hi[m*32 + sa*8];
      al[f] = *(const short8*)&As_lo[m*32 + sa*8];
      int j  = wn*64 + f*16 + ml;
      int sb = gk ^ ((j>>1)&3);
      bh[f] = *(const short8*)&Bs_hi[j*32 + sb*8];
      bl[f] = *(const short8*)&Bs_lo[j*32 + sb*8];
    }
    for (int fm=0; fm<4; ++fm)
      for (int fn=0; fn<4; ++fn) {
        acc[fm][fn] = __builtin_amdgcn_mfma_f32_16x16x32_bf16(ah[fm], bh[fn], acc[fm][fn], 0, 0, 0);
        acc[fm][fn] = __builtin_amdgcn_mfma_f32_16x16x32_bf16(al[fm], bh[fn], acc[fm][fn], 0, 0, 0);
        acc[fm][fn] = __builtin_amdgcn_mfma_f32_16x16x32_bf16(ah[fm], bl[fn], acc[fm][fn], 0, 0, 0);
      }
    __syncthreads();
  }

  for (int fm=0; fm<4; ++fm) {
    int rbase = row0 + wm*64 + fm*16 + gk*4;
    for (int fn=0; fn<4; ++fn) {
      int ccol = col0 + wn*64 + fn*16 + ml;
      float bv = bias ? bias[ccol] : 0.f;
      for (int i=0;i<4;++i) {
        float f = acc[fm][fn][i] + bv;
        size_t idx = (size_t)(rbase+i)*256 + ccol;
        u16 h = f2bf(f);
        Chi[idx] = h;
        if (Clo) Clo[idx] = f2bf(f - bf2f(h));
      }
    }
  }
}

// ---------------- dual GEMM: x = A@Wp + bp ; xl = A@W2 + b2 ----------------
// A = Ahi+Alo [131072,256] bf16 K-contig; Bp=WpT_hi, B2=W2T_hi [256,256] bf16 (N-major rows of K).
// 2-product scheme: acc = Ah*Bh + Al*Bh (B quantization error ~1e-3, acceptable).
// BM=64, BN=256(full), BK=32; 4 waves, each 64 rows x 64 cols.
// Xhi may alias Ahi and XL may alias Alo: each block writes only its own 64 rows,
// after all its K-step reads of those rows (per-block self-overlay; no restrict on these).
__global__ __launch_bounds__(256) void gemm_dual(const u16* Ahi, const u16* Alo,
                                                 const u16* __restrict__ Bp, const u16* __restrict__ B2,
                                                 const float* __restrict__ bias1, const float* __restrict__ bias2,
                                                 u16* Xhi, u16* Xlo, u16* XL)
{
  __shared__ u16 As_hi[64*32];
  __shared__ u16 As_lo[64*32];
  __shared__ u16 Bs_p[256*32];
  __shared__ u16 Bs_2[256*32];
  const int tid = threadIdx.x, wid = tid>>6, lane = tid&63;
  const int row0 = blockIdx.x*64;
  const int gk = lane>>4, ml = lane&15;

  f32x4 xacc[4][4], lacc[4][4];
  for (int i=0;i<4;++i) for (int j=0;j<4;++j) for (int e=0;e<4;++e){ xacc[i][j][e]=0.f; lacc[i][j][e]=0.f; }

  for (int kt=0; kt<256; kt+=32) {
    // stage A tiles: 256 chunks (64 rows x 4), one instr/thread
    {
      int q = tid, m = q>>2, sc = q&3;
      int gs = sc ^ ((m>>1)&3);
      int qb = wid*64;
      __builtin_amdgcn_global_load_lds(AS1C(Ahi + (size_t)(row0+m)*256 + kt + gs*8),
                                       AS3(As_hi + (size_t)qb*8), 16, 0, 0);
      __builtin_amdgcn_global_load_lds(AS1C(Alo + (size_t)(row0+m)*256 + kt + gs*8),
                                       AS3(As_lo + (size_t)qb*8), 16, 0, 0);
    }
    // stage B tiles: 1024 chunks each (256 rows x 4), 4 instr/thread
    for (int it=0; it<4; ++it) {
      int qb = it*256 + wid*64;
      int q  = qb + lane;
      int m  = q>>2, sc = q&3;
      int gs = sc ^ ((m>>1)&3);
      __builtin_amdgcn_global_load_lds(AS1C(Bp + (size_t)m*256 + kt + gs*8),
                                       AS3(Bs_p + (size_t)qb*8), 16, 0, 0);
      __builtin_amdgcn_global_load_lds(AS1C(B2 + (size_t)m*256 + kt + gs*8),
                                       AS3(Bs_2 + (size_t)qb*8), 16, 0, 0);
    }
    asm volatile("s_waitcnt vmcnt(0)" ::: "memory");
    __syncthreads();

    short8 ah[4], al[4];
    for (int f=0; f<4; ++f) {
      int m  = f*16 + ml;
      int sa = gk ^ ((m>>1)&3);
      ah[f] = *(const short8*)&As_hi[m*32 + sa*8];
      al[f] = *(const short8*)&As_lo[m*32 + sa*8];
    }
    for (int fn=0; fn<4; ++fn) {
      int j  = wid*64 + fn*16 + ml;
      int sb = gk ^ ((j>>1)&3);
      short8 bp8 = *(const short8*)&Bs_p[j*32 + sb*8];
      short8 b28 = *(const short8*)&Bs_2[j*32 + sb*8];
      for (int fm=0; fm<4; ++fm) {
        xacc[fm][fn] = __builtin_amdgcn_mfma_f32_16x16x32_bf16(ah[fm], bp8, xacc[fm][fn], 0, 0, 0);
        xacc[fm][fn] = __builtin_amdgcn_mfma_f32_16x16x32_bf16(al[fm], bp8, xacc[fm][fn], 0, 0, 0);
        lacc[fm][fn] = __builtin_amdgcn_mfma_f32_16x16x32_bf16(ah[fm], b28, lacc[fm][fn], 0, 0, 0);
        lacc[fm][fn] = __builtin_amdgcn_mfma_f32_16x16x32_bf16(al[fm], b28, lacc[fm][fn], 0, 0, 0);
      }
    }
    __syncthreads();
  }

  for (int fn=0; fn<4; ++fn) {
    int col = wid*64 + fn*16 + ml;
    float b1 = bias1 ? bias1[col] : 0.f;
    float b2 = bias2 ? bias2[col] : 0.f;
    for (int fm=0; fm<4; ++fm) {
      int rbase = row0 + fm*16 + gk*4;
      for (int i=0;i<4;++i) {
        size_t idx = (size_t)(rbase+i)*256 + col;
        float xv = xacc[fm][fn][i] + b1;
        u16 h = f2bf(xv);
        Xhi[idx] = h;
        if (Xlo) Xlo[idx] = f2bf(xv - bf2f(h));
        XL[idx] = f2bf(lacc[fm][fn][i] + b2);
      }
    }
  }
}

// ---------------- graph prep ----------------
__global__ void fill_all(const int* __restrict__ row, const int* __restrict__ col,
                         int* __restrict__ cur, int* __restrict__ bucket){
  int e = blockIdx.x*256 + threadIdx.x;
  if (e >= EEDG) return;
  int c = col[e];
  int s = atomicAdd(&cur[c], 1);
  if (s < CAP) bucket[(size_t)c*CAP + s] = row[e];
}
__global__ void calc_dinv(const int* __restrict__ cnt, float* __restrict__ dinv){
  int n = blockIdx.x*256 + threadIdx.x;
  if (n < NNODE) dinv[n] = rsqrtf((float)cnt[n] + 1.0f);
}

// ---------------- fused: aggregate + bg + GELU + residual + LN + head logits ----------------
__global__ __launch_bounds__(256) void fused_agg(
    const u16* __restrict__ xl, const u16* __restrict__ xhi, const u16* __restrict__ xlo,
    const int* __restrict__ cnt, const float* __restrict__ dinv, const int* __restrict__ bucket,
    const float* __restrict__ bgv, const float* __restrict__ gam, const float* __restrict__ bet,
    const float* __restrict__ qv, float* __restrict__ outg, float* __restrict__ logits)
{
  const int wid = threadIdx.x>>6, lane = threadIdx.x&63;
  const int half = lane>>5, sl = lane&31;
  const int n = blockIdx.x*8 + wid*2 + half;
  const int c0 = sl*8;
  const float dn = dinv[n];
  int lim = cnt[n]; if (lim > CAP) lim = CAP;

  int rl = bucket[(size_t)n*CAP + sl];
  if (sl >= lim) rl = n;
  float wl = (sl < lim) ? dinv[rl]*dn : 0.0f;

  float a[8];
  {
    uint4 q = *(const uint4*)(xl + (size_t)n*256 + c0);
    unpack8(q, a);
    float wself = dn*dn;
    #pragma unroll
    for (int j=0;j<8;++j) a[j] *= wself;
  }

  for (int s=0; s<lim; s+=2) {
    int  src0 = half*32 + s;
    int  r0   = __shfl(rl, src0);
    float w0  = __shfl(wl, src0);
    bool p1   = (s+1 < lim);
    int  src1 = half*32 + (p1 ? s+1 : s);
    int  r1   = __shfl(rl, src1);
    float w1  = p1 ? __shfl(wl, src1) : 0.0f;
    uint4 q0 = *(const uint4*)(xl + (size_t)r0*256 + c0);
    uint4 q1 = *(const uint4*)(xl + (size_t)r1*256 + c0);
    float f0[8], f1[8];
    unpack8(q0, f0); unpack8(q1, f1);
    #pragma unroll
    for (int j=0;j<8;++j) a[j] += f0[j]*w0 + f1[j]*w1;
  }

  float xv[8];
  {
    uint4 qh = *(const uint4*)(xhi + (size_t)n*256 + c0);
    unpack8(qh, xv);
    if (xlo) {
      uint4 ql = *(const uint4*)(xlo + (size_t)n*256 + c0);
      float xw[8]; unpack8(ql, xw);
      #pragma unroll
      for (int j=0;j<8;++j) xv[j] += xw[j];
    }
  }

  float4 b0 = *(const float4*)(bgv + c0), b1 = *(const float4*)(bgv + c0 + 4);
  float bgs[8] = {b0.x,b0.y,b0.z,b0.w,b1.x,b1.y,b1.z,b1.w};
  float g[8];
  float s1 = 0.f, s2 = 0.f;
  #pragma unroll
  for (int j=0;j<8;++j){
    g[j] = gelu_exact(a[j] + bgs[j]) + xv[j];
    s1 += g[j]; s2 += g[j]*g[j];
  }
  #pragma unroll
  for (int off=16; off; off>>=1){ s1 += __shfl_xor(s1, off); s2 += __shfl_xor(s2, off); }
  float mu  = s1*(1.0f/256.0f);
  float var = s2*(1.0f/256.0f) - mu*mu;
  float inv = rsqrtf(var + 1e-5f);

  float4 g0 = *(const float4*)(gam + c0), g1 = *(const float4*)(gam + c0 + 4);
  float4 e0 = *(const float4*)(bet + c0), e1 = *(const float4*)(bet + c0 + 4);
  float gms[8] = {g0.x,g0.y,g0.z,g0.w,g1.x,g1.y,g1.z,g1.w};
  float bts[8] = {e0.x,e0.y,e0.z,e0.w,e1.x,e1.y,e1.z,e1.w};
  float y[8];
  #pragma unroll
  for (int j=0;j<8;++j) y[j] = (g[j]-mu)*inv*gms[j] + bts[j];

  float4 o0 = {y[0],y[1],y[2],y[3]}, o1 = {y[4],y[5],y[6],y[7]};
  *reinterpret_cast<float4*>(outg + (size_t)n*256 + c0)     = o0;
  *reinterpret_cast<float4*>(outg + (size_t)n*256 + c0 + 4) = o1;

  float4 q0 = *(const float4*)(qv + c0), q1 = *(const float4*)(qv + c0 + 4);
  float qs[8] = {q0.x,q0.y,q0.z,q0.w,q1.x,q1.y,q1.z,q1.w};
  float dq = 0.f;
  #pragma unroll
  for (int j=0;j<8;++j) dq += y[j]*qs[j];
  dq += __shfl_xor(dq,1); dq += __shfl_xor(dq,2);
  if ((sl&3)==0){
    int b = n>>12, p = n&4095, h = sl>>2;
    logits[(size_t)(b*8+h)*4096 + p] = dq*10.0f;   // 1/TEMPERATURE
  }
}

// ---------------- row softmax over 4096 (fp32 in/out) ----------------
__global__ __launch_bounds__(256) void softmax_rows(const float* __restrict__ logits, float* __restrict__ outa){
  int r = blockIdx.x;
  const float* p = logits + (size_t)r*4096;
  int tid = threadIdx.x;
  int wid = tid>>6, lane = tid&63;
  __shared__ float redm[4];
  __shared__ float reds[4];
  float v[16];
  float mx = -1e30f;
  for (int i=0;i<16;++i){ v[i] = p[tid + i*256]; mx = fmaxf(mx, v[i]); }
  for (int off=32; off; off>>=1) mx = fmaxf(mx, __shfl_xor(mx, off));
  if (lane==0) redm[wid]=mx;
  __syncthreads();
  mx = fmaxf(fmaxf(redm[0],redm[1]), fmaxf(redm[2],redm[3]));
  float sum = 0.f;
  for (int i=0;i<16;++i){ v[i] = expf(v[i]-mx); sum += v[i]; }
  for (int off=32; off; off>>=1) sum += __shfl_xor(sum, off);
  if (lane==0) reds[wid]=sum;
  __syncthreads();
  sum = reds[0]+reds[1]+reds[2]+reds[3];
  float rinv = 1.0f/sum;
  for (int i=0;i<16;++i) outa[(size_t)r*4096 + tid + i*256] = v[i]*rinv;
}

extern "C" void kernel_launch(void* const* d_in, const int* in_sizes, int n_in,
                              void* d_out, int out_size, void* d_ws, size_t ws_size,
                              hipStream_t stream)
{
  const float* img  = (const float*)d_in[0];
  const int* edges  = (const int*)d_in[1];   // [2][E] int32: row=edges, col=edges+E
  const float* Wp   = (const float*)d_in[2];
  const float* bp   = (const float*)d_in[3];
  const float* Wg   = (const float*)d_in[4];
  const float* bg   = (const float*)d_in[5];
  const float* lng  = (const float*)d_in[6];
  const float* lnb  = (const float*)d_in[7];
  const float* dq   = (const float*)d_in[8];
  char* ws = (char*)d_ws;

  constexpr size_t REG   = (size_t)NNODE*CC*2;     // 67,108,864
  constexpr size_t WBLK  = 9u*131072 + 1024;       // 8 weight arrays + bias2 (rounded below)
  constexpr size_t WBLKA = 1245184;                // 1.19 MB aligned
  constexpr size_t GBLK  = 524288u*2 + (size_t)NNODE*CAP*4 + (size_t)256*4096*4; // ~21.8 MB
  const bool full = (ws_size >= 3*REG + WBLKA + GBLK);
  if (!full && ws_size < 2*REG + WBLKA + GBLK) return;

  u16* AT_hi = (u16*)(ws + 0);          // -> becomes x_hi after gemm_dual
  u16* AT_lo = (u16*)(ws + REG);        // -> becomes xl after gemm_dual
  u16* x_lo  = full ? (u16*)(ws + 2*REG) : nullptr;
  char* wblk = ws + (full ? 3 : 2)*REG;
  char* gblk = wblk + WBLKA;

  u16* Wp_hi  = (u16*)(wblk + 0*131072);
  u16* Wp_lo  = (u16*)(wblk + 1*131072);
  u16* WpT_hi = (u16*)(wblk + 2*131072);
  u16* WpT_lo = (u16*)(wblk + 3*131072);
  u16* WgT_hi = (u16*)(wblk + 4*131072);
  u16* WgT_lo = (u16*)(wblk + 5*131072);
  u16* W2T_hi = (u16*)(wblk + 6*131072);
  u16* W2T_lo = (u16*)(wblk + 7*131072);
  float* bias2 = (float*)(wblk + 8*131072);

  int*   cur    = (int*)(gblk);
  float* dinv   = (float*)(gblk + 524288);
  int*   bucket = (int*)(gblk + 1048576);
  float* logits = (float*)(gblk + 1048576 + (size_t)NNODE*CAP*4);

  // --- weight prep (all tiny) ---
  split_rm       <<<64, 256, 0, stream>>>(Wp, Wp_hi, Wp_lo);
  transpose_split<<<dim3(4,4,1), 256, 0, stream>>>(Wp, WpT_hi, WpT_lo, 256, 256, 0, 0);
  transpose_split<<<dim3(4,4,1), 256, 0, stream>>>(Wg, WgT_hi, WgT_lo, 256, 256, 0, 0);
  // W2T = WgT @ Wp^T-form: C[m,n] = sum_k WgT[m,k]*Wp[n,k] = (Wp@Wg)[n,m]
  gemm_split     <<<dim3(2,2), 256, 0, stream>>>(WgT_hi, WgT_lo, Wp_hi, Wp_lo, nullptr, W2T_hi, W2T_lo);
  bias2_k        <<<1, 256, 0, stream>>>(bp, Wg, bias2);

  // --- img transpose+split ---
  transpose_split<<<dim3(64,4,32), 256, 0, stream>>>(img, AT_hi, AT_lo, 256, 4096,
                                                     (size_t)CC*HWSZ, (size_t)HWSZ*CC);

  // --- graph prep ---
  hipMemsetAsync(cur, 0, 524288, stream);
  fill_all <<<2048, 256, 0, stream>>>(edges, edges+EEDG, cur, bucket);
  calc_dinv<<<512,  256, 0, stream>>>(cur, dinv);

  // --- dual GEMM: x (hi->AT_hi, lo->x_lo) and xl (->AT_lo) ---
  gemm_dual<<<NNODE/64, 256, 0, stream>>>(AT_hi, AT_lo, WpT_hi, W2T_hi, bp, bias2,
                                          AT_hi, x_lo, AT_lo);

  float* outg = (float*)d_out;
  float* outa = (float*)d_out + (size_t)NNODE*CC;
  fused_agg<<<NNODE/8, 256, 0, stream>>>(AT_lo, AT_hi, x_lo, cur, dinv, bucket,
                                         bg, lng, lnb, dq, outg, logits);
  softmax_rows<<<256, 256, 0, stream>>>(logits, outa);
}

// Round 5
// 292.804 us; speedup vs baseline: 1.3786x; 1.3786x over previous
//
#include <hip/hip_runtime.h>

typedef unsigned short u16;
typedef __attribute__((ext_vector_type(8))) short short8;
typedef __attribute__((ext_vector_type(16))) float f32x16;

#define AS1C(p) ((const __attribute__((address_space(1))) void*)(p))
#define AS3(p)  ((__attribute__((address_space(3))) void*)(p))

constexpr int CC    = 256;      // channels
constexpr int HWSZ  = 4096;     // H*W
constexpr int NNODE = 131072;   // B*H*W
constexpr int EEDG  = 524288;   // edges
constexpr int CAP   = 32;       // per-node bucket capacity

__device__ __forceinline__ float bf2f(u16 h){ unsigned u = ((unsigned)h)<<16; float f; __builtin_memcpy(&f,&u,4); return f; }
__device__ __forceinline__ u16 f2bf(float f){ unsigned u; __builtin_memcpy(&u,&f,4); return (u16)((u + 0x7FFFu + ((u>>16)&1u))>>16); }
__device__ __forceinline__ float gelu_exact(float v){ return 0.5f*v*(1.0f + erff(v*0.7071067811865476f)); }

__device__ __forceinline__ void unpack8(uint4 q, float f[8]){
  unsigned w0=q.x,w1=q.y,w2=q.z,w3=q.w;
  unsigned l0=w0<<16, h0=w0&0xffff0000u, l1=w1<<16, h1=w1&0xffff0000u;
  unsigned l2=w2<<16, h2=w2&0xffff0000u, l3=w3<<16, h3=w3&0xffff0000u;
  __builtin_memcpy(&f[0],&l0,4); __builtin_memcpy(&f[1],&h0,4);
  __builtin_memcpy(&f[2],&l1,4); __builtin_memcpy(&f[3],&h1,4);
  __builtin_memcpy(&f[4],&l2,4); __builtin_memcpy(&f[5],&h2,4);
  __builtin_memcpy(&f[6],&l3,4); __builtin_memcpy(&f[7],&h3,4);
}

// ---------------- fp32 64x64 tiled transpose + bf16 hi/lo split ----------------
__global__ __launch_bounds__(256) void transpose_split(const float* __restrict__ src,
                                                       u16* __restrict__ dhi, u16* __restrict__ dlo,
                                                       int R, int Ccols, size_t sb_in, size_t sb_out)
{
  __shared__ float t[64][65];
  const float* s = src + blockIdx.z*sb_in + (size_t)(blockIdx.y*64)*Ccols + blockIdx.x*64;
  size_t obase   = blockIdx.z*sb_out + (size_t)(blockIdx.x*64)*R + blockIdx.y*64;
  int tid = threadIdx.x;
  for (int i=0;i<4;++i){
    int idx = i*256 + tid;
    int r = idx>>4, q = idx&15;
    float4 v = *(const float4*)(s + (size_t)r*Ccols + q*4);
    t[r][q*4+0]=v.x; t[r][q*4+1]=v.y; t[r][q*4+2]=v.z; t[r][q*4+3]=v.w;
  }
  __syncthreads();
  for (int i=0;i<2;++i){
    int idx = i*256 + tid;
    int rr = idx>>3, ch = idx&7;
    u16 hi[8], lo[8];
    for (int j=0;j<8;++j){
      float f = t[ch*8+j][rr];
      u16 h = f2bf(f); hi[j] = h;
      lo[j] = f2bf(f - bf2f(h));
    }
    *(uint4*)(dhi + obase + (size_t)rr*R + ch*8) = *(uint4*)hi;
    if (dlo) *(uint4*)(dlo + obase + (size_t)rr*R + ch*8) = *(uint4*)lo;
  }
}

// ---------------- 2-product GEMM, 32x32x16 MFMA ----------------
// C[m,n] = sum_k (Ahi[+Alo])[m,k] * Bt[n,k] + bias[n]
// BM=BN=128, BK=32; 4 waves, each 64x64 = 2x2 fragments of 32x32.
// C layout: col=lane&31, row=(reg&3)+8*(reg>>2)+4*(lane>>5) -> 64B-sector stores.
// Chi may alias Alo/Ahi per-block (epilogue after all reads of own rows).
__global__ __launch_bounds__(256,2) void gemm2p(const u16* Ahi, const u16* Alo,
                                                const u16* __restrict__ Bt,
                                                const float* __restrict__ bias,
                                                u16* Chi)
{
  __shared__ u16 As_hi[128*32];
  __shared__ u16 As_lo[128*32];
  __shared__ u16 Bs[128*32];
  const int tid = threadIdx.x, wid = tid>>6, lane = tid&63;
  const int row0 = blockIdx.x*128, col0 = blockIdx.y*128;
  const int wm = wid>>1, wn = wid&1;
  const int l31 = lane&31, lh = lane>>5;
  const bool haslo = (Alo != nullptr);

  f32x16 acc[2][2];
  #pragma unroll
  for (int i=0;i<2;++i)
    #pragma unroll
    for (int j=0;j<2;++j)
      #pragma unroll
      for (int e=0;e<16;++e) acc[i][j][e]=0.f;

  for (int kt=0; kt<256; kt+=32) {
#define STAGE(G, S, rbase)                                                            \
    for (int it=0; it<2; ++it) {                                                      \
      int qb = (it*4+wid)*64;                                                         \
      int qq = qb + lane;                                                             \
      int m  = qq>>2, sc = qq&3;                                                      \
      int gs = sc ^ ((m>>1)&3);                                                       \
      __builtin_amdgcn_global_load_lds(AS1C(G + (size_t)((rbase)+m)*256 + kt + gs*8), \
                                       AS3(S + (size_t)qb*8), 16, 0, 0);              \
    }
    STAGE(Ahi, As_hi, row0)
    if (haslo) { STAGE(Alo, As_lo, row0) }
    STAGE(Bt,  Bs,    col0)
#undef STAGE
    asm volatile("s_waitcnt vmcnt(0)" ::: "memory");
    __syncthreads();

    short8 ah[2][2], al[2][2], bfr[2][2];
    #pragma unroll
    for (int fm=0; fm<2; ++fm)
      #pragma unroll
      for (int kh=0; kh<2; ++kh) {
        int row = wm*64 + fm*32 + l31;
        int sa  = (kh*2 + lh) ^ ((row>>1)&3);
        ah[fm][kh] = *(const short8*)&As_hi[row*32 + sa*8];
        if (haslo) al[fm][kh] = *(const short8*)&As_lo[row*32 + sa*8];
      }
    #pragma unroll
    for (int fn=0; fn<2; ++fn)
      #pragma unroll
      for (int kh=0; kh<2; ++kh) {
        int col = wn*64 + fn*32 + l31;
        int sb  = (kh*2 + lh) ^ ((col>>1)&3);
        bfr[fn][kh] = *(const short8*)&Bs[col*32 + sb*8];
      }
    #pragma unroll
    for (int kh=0; kh<2; ++kh)
      #pragma unroll
      for (int fm=0; fm<2; ++fm)
        #pragma unroll
        for (int fn=0; fn<2; ++fn) {
          acc[fm][fn] = __builtin_amdgcn_mfma_f32_32x32x16_bf16(ah[fm][kh], bfr[fn][kh], acc[fm][fn], 0, 0, 0);
          if (haslo)
            acc[fm][fn] = __builtin_amdgcn_mfma_f32_32x32x16_bf16(al[fm][kh], bfr[fn][kh], acc[fm][fn], 0, 0, 0);
        }
    __syncthreads();
  }

  #pragma unroll
  for (int fn=0; fn<2; ++fn) {
    int col = col0 + wn*64 + fn*32 + l31;
    float bv = bias ? bias[col] : 0.f;
    #pragma unroll
    for (int fm=0; fm<2; ++fm) {
      int rbase = row0 + wm*64 + fm*32 + 4*lh;
      #pragma unroll
      for (int reg=0; reg<16; ++reg) {
        int row = rbase + (reg&3) + 8*(reg>>2);
        Chi[(size_t)row*256 + col] = f2bf(acc[fm][fn][reg] + bv);
      }
    }
  }
}

// ---------------- graph prep ----------------
__global__ void fill_all(const int* __restrict__ row, const int* __restrict__ col,
                         int* __restrict__ cur, int* __restrict__ bucket){
  int e = blockIdx.x*256 + threadIdx.x;
  if (e >= EEDG) return;
  int c = col[e];
  int s = atomicAdd(&cur[c], 1);
  if (s < CAP) bucket[(size_t)c*CAP + s] = row[e];
}
__global__ void calc_dinv(const int* __restrict__ cnt, float* __restrict__ dinv){
  int n = blockIdx.x*256 + threadIdx.x;
  if (n < NNODE) dinv[n] = rsqrtf((float)cnt[n] + 1.0f);
}

// ---------------- fused: aggregate + bg + GELU + residual + LN + head logits ----------------
__global__ __launch_bounds__(256) void fused_agg(
    const u16* __restrict__ xl, const u16* __restrict__ xhi,
    const int* __restrict__ cnt, const float* __restrict__ dinv, const int* __restrict__ bucket,
    const float* __restrict__ bgv, const float* __restrict__ gam, const float* __restrict__ bet,
    const float* __restrict__ qv, float* __restrict__ outg, float* __restrict__ logits)
{
  const int wid = threadIdx.x>>6, lane = threadIdx.x&63;
  const int half = lane>>5, sl = lane&31;
  const int n = blockIdx.x*8 + wid*2 + half;
  const int c0 = sl*8;
  const float dn = dinv[n];
  int lim = cnt[n]; if (lim > CAP) lim = CAP;

  int rl = bucket[(size_t)n*CAP + sl];
  if (sl >= lim) rl = n;                 // sanitize poison slots
  float wl = (sl < lim) ? dinv[rl]*dn : 0.0f;

  float a[8];
  {
    uint4 q = *(const uint4*)(xl + (size_t)n*256 + c0);
    unpack8(q, a);
    float wself = dn*dn;
    #pragma unroll
    for (int j=0;j<8;++j) a[j] *= wself;
  }

  int limR = (lim + 3) & ~3;
  for (int s=0; s<limR; s+=4) {
    int b0 = half*32 + s;
    int  r0 = __shfl(rl, b0),   r1 = __shfl(rl, b0+1);
    int  r2 = __shfl(rl, b0+2), r3 = __shfl(rl, b0+3);
    float w0 = __shfl(wl, b0),   w1 = __shfl(wl, b0+1);
    float w2 = __shfl(wl, b0+2), w3 = __shfl(wl, b0+3);
    uint4 q0 = *(const uint4*)(xl + (size_t)r0*256 + c0);
    uint4 q1 = *(const uint4*)(xl + (size_t)r1*256 + c0);
    uint4 q2 = *(const uint4*)(xl + (size_t)r2*256 + c0);
    uint4 q3 = *(const uint4*)(xl + (size_t)r3*256 + c0);
    float f0[8], f1[8], f2[8], f3[8];
    unpack8(q0, f0); unpack8(q1, f1); unpack8(q2, f2); unpack8(q3, f3);
    #pragma unroll
    for (int j=0;j<8;++j) a[j] += f0[j]*w0 + f1[j]*w1 + f2[j]*w2 + f3[j]*w3;
  }

  float xv[8];
  {
    uint4 qh = *(const uint4*)(xhi + (size_t)n*256 + c0);
    unpack8(qh, xv);
  }

  float4 b0 = *(const float4*)(bgv + c0), b1 = *(const float4*)(bgv + c0 + 4);
  float bgs[8] = {b0.x,b0.y,b0.z,b0.w,b1.x,b1.y,b1.z,b1.w};
  float g[8];
  float s1 = 0.f, s2 = 0.f;
  #pragma unroll
  for (int j=0;j<8;++j){
    g[j] = gelu_exact(a[j] + bgs[j]) + xv[j];
    s1 += g[j]; s2 += g[j]*g[j];
  }
  #pragma unroll
  for (int off=16; off; off>>=1){ s1 += __shfl_xor(s1, off); s2 += __shfl_xor(s2, off); }
  float mu  = s1*(1.0f/256.0f);
  float var = s2*(1.0f/256.0f) - mu*mu;
  float inv = rsqrtf(var + 1e-5f);

  float4 g0 = *(const float4*)(gam + c0), g1 = *(const float4*)(gam + c0 + 4);
  float4 e0 = *(const float4*)(bet + c0), e1 = *(const float4*)(bet + c0 + 4);
  float gms[8] = {g0.x,g0.y,g0.z,g0.w,g1.x,g1.y,g1.z,g1.w};
  float bts[8] = {e0.x,e0.y,e0.z,e0.w,e1.x,e1.y,e1.z,e1.w};
  float y[8];
  #pragma unroll
  for (int j=0;j<8;++j) y[j] = (g[j]-mu)*inv*gms[j] + bts[j];

  float4 o0 = {y[0],y[1],y[2],y[3]}, o1 = {y[4],y[5],y[6],y[7]};
  *reinterpret_cast<float4*>(outg + (size_t)n*256 + c0)     = o0;
  *reinterpret_cast<float4*>(outg + (size_t)n*256 + c0 + 4) = o1;

  float4 q0 = *(const float4*)(qv + c0), q1 = *(const float4*)(qv + c0 + 4);
  float qs[8] = {q0.x,q0.y,q0.z,q0.w,q1.x,q1.y,q1.z,q1.w};
  float dq = 0.f;
  #pragma unroll
  for (int j=0;j<8;++j) dq += y[j]*qs[j];
  dq += __shfl_xor(dq,1); dq += __shfl_xor(dq,2);
  if ((sl&3)==0){
    int b = n>>12, p = n&4095, h = sl>>2;
    logits[(size_t)(b*8+h)*4096 + p] = dq*10.0f;   // 1/TEMPERATURE
  }
}

// ---------------- row softmax over 4096 (fp32 in/out) ----------------
__global__ __launch_bounds__(256) void softmax_rows(const float* __restrict__ logits, float* __restrict__ outa){
  int r = blockIdx.x;
  const float* p = logits + (size_t)r*4096;
  int tid = threadIdx.x;
  int wid = tid>>6, lane = tid&63;
  __shared__ float redm[4];
  __shared__ float reds[4];
  float v[16];
  float mx = -1e30f;
  for (int i=0;i<16;++i){ v[i] = p[tid + i*256]; mx = fmaxf(mx, v[i]); }
  for (int off=32; off; off>>=1) mx = fmaxf(mx, __shfl_xor(mx, off));
  if (lane==0) redm[wid]=mx;
  __syncthreads();
  mx = fmaxf(fmaxf(redm[0],redm[1]), fmaxf(redm[2],redm[3]));
  float sum = 0.f;
  for (int i=0;i<16;++i){ v[i] = expf(v[i]-mx); sum += v[i]; }
  for (int off=32; off; off>>=1) sum += __shfl_xor(sum, off);
  if (lane==0) reds[wid]=sum;
  __syncthreads();
  sum = reds[0]+reds[1]+reds[2]+reds[3];
  float rinv = 1.0f/sum;
  for (int i=0;i<16;++i) outa[(size_t)r*4096 + tid + i*256] = v[i]*rinv;
}

extern "C" void kernel_launch(void* const* d_in, const int* in_sizes, int n_in,
                              void* d_out, int out_size, void* d_ws, size_t ws_size,
                              hipStream_t stream)
{
  const float* img  = (const float*)d_in[0];
  const int* edges  = (const int*)d_in[1];   // [2][E] int32: row=edges, col=edges+E
  const float* Wp   = (const float*)d_in[2];
  const float* bp   = (const float*)d_in[3];
  const float* Wg   = (const float*)d_in[4];
  const float* bg   = (const float*)d_in[5];
  const float* lng  = (const float*)d_in[6];
  const float* lnb  = (const float*)d_in[7];
  const float* dq   = (const float*)d_in[8];
  char* ws = (char*)d_ws;

  constexpr size_t REG  = (size_t)NNODE*CC*2;                                   // 67,108,864
  constexpr size_t WTS  = 2u*131072;
  constexpr size_t GBLK = 524288u*2 + (size_t)NNODE*CAP*4 + (size_t)256*4096*4; // ~21.8 MB
  const bool mid = (ws_size >= 3*REG + WTS + GBLK);
  if (!mid && ws_size < 2*REG + WTS + GBLK) return;

  u16* AT_hi = (u16*)(ws + 0);                     // -> xl after GEMM2
  u16* AT_lo = (u16*)(ws + REG);                   // lean: -> x_hi after GEMM1 (self-overlay)
  u16* x_hi  = mid ? (u16*)(ws + 2*REG) : AT_lo;
  char* wts  = ws + (mid ? 3 : 2)*REG;
  char* gblk = wts + WTS;

  u16* WpT_hi = (u16*)(wts);
  u16* WgT_hi = (u16*)(wts + 131072);
  int*   cur    = (int*)(gblk);
  float* dinv   = (float*)(gblk + 524288);
  int*   bucket = (int*)(gblk + 1048576);
  float* logits = (float*)(gblk + 1048576 + (size_t)NNODE*CAP*4);

  transpose_split<<<dim3(4,4,1), 256, 0, stream>>>(Wp, WpT_hi, nullptr, 256, 256, 0, 0);
  transpose_split<<<dim3(4,4,1), 256, 0, stream>>>(Wg, WgT_hi, nullptr, 256, 256, 0, 0);
  transpose_split<<<dim3(64,4,32), 256, 0, stream>>>(img, AT_hi, AT_lo, 256, 4096,
                                                     (size_t)CC*HWSZ, (size_t)HWSZ*CC);

  hipMemsetAsync(cur, 0, 524288, stream);
  fill_all <<<2048, 256, 0, stream>>>(edges, edges+EEDG, cur, bucket);
  calc_dinv<<<512,  256, 0, stream>>>(cur, dinv);

  // x = imgT @ Wp + bp  (2-product: img hi+lo, Wp hi)
  gemm2p<<<dim3(1024,2), 256, 0, stream>>>(AT_hi, AT_lo, WpT_hi, bp, x_hi);
  // xl = x @ Wg  (1-product: x hi, Wg hi) -> overwrites AT_hi (dead)
  gemm2p<<<dim3(1024,2), 256, 0, stream>>>(x_hi, nullptr, WgT_hi, nullptr, AT_hi);

  float* outg = (float*)d_out;
  float* outa = (float*)d_out + (size_t)NNODE*CC;
  fused_agg<<<NNODE/8, 256, 0, stream>>>(AT_hi, x_hi, cur, dinv, bucket,
                                         bg, lng, lnb, dq, outg, logits);
  softmax_rows<<<256, 256, 0, stream>>>(logits, outa);
}

// Round 6
// 242.508 us; speedup vs baseline: 1.6646x; 1.2074x over previous
//
#include <hip/hip_runtime.h>

typedef unsigned short u16;
typedef __attribute__((ext_vector_type(8))) short short8;
typedef __attribute__((ext_vector_type(4))) float f32x4;
typedef __attribute__((ext_vector_type(16))) float f32x16;

#define AS1C(p) ((const __attribute__((address_space(1))) void*)(p))
#define AS3(p)  ((__attribute__((address_space(3))) void*)(p))

constexpr int CC    = 256;      // channels
constexpr int HWSZ  = 4096;     // H*W
constexpr int NNODE = 131072;   // B*H*W
constexpr int EEDG  = 524288;   // edges
constexpr int CAP   = 32;       // per-node bucket capacity

__device__ __forceinline__ float bf2f(u16 h){ unsigned u = ((unsigned)h)<<16; float f; __builtin_memcpy(&f,&u,4); return f; }
__device__ __forceinline__ u16 f2bf(float f){ unsigned u; __builtin_memcpy(&u,&f,4); return (u16)((u + 0x7FFFu + ((u>>16)&1u))>>16); }
__device__ __forceinline__ float gelu_exact(float v){ return 0.5f*v*(1.0f + erff(v*0.7071067811865476f)); }

__device__ __forceinline__ void unpack8(uint4 q, float f[8]){
  unsigned w0=q.x,w1=q.y,w2=q.z,w3=q.w;
  unsigned l0=w0<<16, h0=w0&0xffff0000u, l1=w1<<16, h1=w1&0xffff0000u;
  unsigned l2=w2<<16, h2=w2&0xffff0000u, l3=w3<<16, h3=w3&0xffff0000u;
  __builtin_memcpy(&f[0],&l0,4); __builtin_memcpy(&f[1],&h0,4);
  __builtin_memcpy(&f[2],&l1,4); __builtin_memcpy(&f[3],&h1,4);
  __builtin_memcpy(&f[4],&l2,4); __builtin_memcpy(&f[5],&h2,4);
  __builtin_memcpy(&f[6],&l3,4); __builtin_memcpy(&f[7],&h3,4);
}

// ---------------- fp32 64x64 tiled transpose -> bf16 hi (for weights) ----------------
__global__ __launch_bounds__(256) void transpose_split(const float* __restrict__ src,
                                                       u16* __restrict__ dhi, u16* __restrict__ dlo,
                                                       int R, int Ccols, size_t sb_in, size_t sb_out)
{
  __shared__ float t[64][65];
  const float* s = src + blockIdx.z*sb_in + (size_t)(blockIdx.y*64)*Ccols + blockIdx.x*64;
  size_t obase   = blockIdx.z*sb_out + (size_t)(blockIdx.x*64)*R + blockIdx.y*64;
  int tid = threadIdx.x;
  for (int i=0;i<4;++i){
    int idx = i*256 + tid;
    int r = idx>>4, q = idx&15;
    float4 v = *(const float4*)(s + (size_t)r*Ccols + q*4);
    t[r][q*4+0]=v.x; t[r][q*4+1]=v.y; t[r][q*4+2]=v.z; t[r][q*4+3]=v.w;
  }
  __syncthreads();
  for (int i=0;i<2;++i){
    int idx = i*256 + tid;
    int rr = idx>>3, ch = idx&7;
    u16 hi[8], lo[8];
    for (int j=0;j<8;++j){
      float f = t[ch*8+j][rr];
      u16 h = f2bf(f); hi[j] = h;
      lo[j] = f2bf(f - bf2f(h));
    }
    *(uint4*)(dhi + obase + (size_t)rr*R + ch*8) = *(uint4*)hi;
    if (dlo) *(uint4*)(dlo + obase + (size_t)rr*R + ch*8) = *(uint4*)lo;
  }
}

// ---------------- GEMM1 fused with transpose: x = imgT @ Wp + bp ----------------
// A read DIRECTLY from img fp32 ([B,C,HW]: tile = 32 contiguous 512B runs, coalesced).
// LDS keeps A fp32 c-major [32][128]; fragment read = 8 scalar ds_read_b32 at
// bank=row%32 (2-way, free), in-register truncation split into bf16 hi/lo.
// 2-product MFMA (Ah*B + Al*B), 32x32x16. 2-phase pipelined (dbuf LDS).
__global__ __launch_bounds__(256,2) void gemm_img(const float* __restrict__ img,
                                                  const u16* __restrict__ Bt,
                                                  const float* __restrict__ bias,
                                                  u16* __restrict__ C)
{
  __shared__ float Afp[2][32*128];
  __shared__ u16   Bs[2][128*32];
  const int tid = threadIdx.x, wid = tid>>6, lane = tid&63;
  const int row0 = blockIdx.x*128, col0 = blockIdx.y*128;
  const int bb = row0 >> 12, hw0 = row0 & 4095;
  const float* abase = img + (size_t)bb*CC*HWSZ + hw0;
  const int wm = wid>>1, wn = wid&1;
  const int l31 = lane&31, lh = lane>>5;

  f32x16 acc[2][2];
  #pragma unroll
  for (int i=0;i<2;++i)
    #pragma unroll
    for (int j=0;j<2;++j)
      #pragma unroll
      for (int e=0;e<16;++e) acc[i][j][e]=0.f;

#define STAGE_IMG(buf, kt)                                                             \
  {                                                                                    \
    _Pragma("unroll")                                                                  \
    for (int it=0; it<4; ++it){                                                        \
      int qb = (it*4+wid)*64;                                                          \
      int q  = qb + lane;                                                              \
      int c  = q>>5, qq = q&31;                                                        \
      __builtin_amdgcn_global_load_lds(AS1C(abase + (size_t)((kt)+c)*HWSZ + qq*4),     \
                                       AS3(&Afp[buf][qb*4]), 16, 0, 0);                \
    }                                                                                  \
    _Pragma("unroll")                                                                  \
    for (int it=0; it<2; ++it){                                                        \
      int qb = (it*4+wid)*64;                                                          \
      int q  = qb + lane;                                                              \
      int m  = q>>2, sc = q&3;                                                         \
      int gs = sc ^ ((m>>1)&3);                                                        \
      __builtin_amdgcn_global_load_lds(AS1C(Bt + (size_t)(col0+m)*256 + (kt) + gs*8),  \
                                       AS3(&Bs[buf][qb*8]), 16, 0, 0);                 \
    }                                                                                  \
  }

  STAGE_IMG(0, 0)
  asm volatile("s_waitcnt vmcnt(0)" ::: "memory");
  __syncthreads();

  for (int t=0; t<8; ++t) {
    int cur = t&1;
    if (t<7) STAGE_IMG(cur^1, (t+1)*32)

    short8 ah[2][2], al[2][2], bfr[2][2];
    #pragma unroll
    for (int fm=0; fm<2; ++fm)
      #pragma unroll
      for (int kh=0; kh<2; ++kh) {
        int r  = wm*64 + fm*32 + l31;
        int cb = kh*16 + lh*8;
        #pragma unroll
        for (int j=0; j<8; ++j) {
          float f = Afp[cur][(cb+j)*128 + r];
          unsigned u; __builtin_memcpy(&u,&f,4);
          ah[fm][kh][j] = (short)(u>>16);
          unsigned uh = u & 0xffff0000u;
          float fh; __builtin_memcpy(&fh,&uh,4);
          float fl = f - fh;
          unsigned ul; __builtin_memcpy(&ul,&fl,4);
          al[fm][kh][j] = (short)(ul>>16);
        }
      }
    #pragma unroll
    for (int fn=0; fn<2; ++fn)
      #pragma unroll
      for (int kh=0; kh<2; ++kh) {
        int col = wn*64 + fn*32 + l31;
        int sb  = (kh*2 + lh) ^ ((col>>1)&3);
        bfr[fn][kh] = *(const short8*)&Bs[cur][col*32 + sb*8];
      }
    #pragma unroll
    for (int kh=0; kh<2; ++kh)
      #pragma unroll
      for (int fm=0; fm<2; ++fm)
        #pragma unroll
        for (int fn=0; fn<2; ++fn) {
          acc[fm][fn] = __builtin_amdgcn_mfma_f32_32x32x16_bf16(ah[fm][kh], bfr[fn][kh], acc[fm][fn], 0, 0, 0);
          acc[fm][fn] = __builtin_amdgcn_mfma_f32_32x32x16_bf16(al[fm][kh], bfr[fn][kh], acc[fm][fn], 0, 0, 0);
        }
    asm volatile("s_waitcnt vmcnt(0)" ::: "memory");
    __syncthreads();
  }
#undef STAGE_IMG

  #pragma unroll
  for (int fn=0; fn<2; ++fn) {
    int col = col0 + wn*64 + fn*32 + l31;
    float bv = bias ? bias[col] : 0.f;
    #pragma unroll
    for (int fm=0; fm<2; ++fm) {
      int rbase = row0 + wm*64 + fm*32 + 4*lh;
      #pragma unroll
      for (int reg=0; reg<16; ++reg) {
        int row = rbase + (reg&3) + 8*(reg>>2);
        C[(size_t)row*256 + col] = f2bf(acc[fm][fn][reg] + bv);
      }
    }
  }
}

// ---------------- GEMM2: xl = x @ Wg  (1-product bf16, 2-phase pipelined) ----------------
__global__ __launch_bounds__(256,2) void gemm1p(const u16* __restrict__ A,
                                                const u16* __restrict__ Bt,
                                                u16* __restrict__ C)
{
  __shared__ u16 As[2][128*32];
  __shared__ u16 Bs[2][128*32];
  const int tid = threadIdx.x, wid = tid>>6, lane = tid&63;
  const int row0 = blockIdx.x*128, col0 = blockIdx.y*128;
  const int wm = wid>>1, wn = wid&1;
  const int l31 = lane&31, lh = lane>>5;

  f32x16 acc[2][2];
  #pragma unroll
  for (int i=0;i<2;++i)
    #pragma unroll
    for (int j=0;j<2;++j)
      #pragma unroll
      for (int e=0;e<16;++e) acc[i][j][e]=0.f;

#define STAGE_AB(buf, kt)                                                              \
  {                                                                                    \
    _Pragma("unroll")                                                                  \
    for (int it=0; it<2; ++it){                                                        \
      int qb = (it*4+wid)*64;                                                          \
      int q  = qb + lane;                                                              \
      int m  = q>>2, sc = q&3;                                                         \
      int gs = sc ^ ((m>>1)&3);                                                        \
      __builtin_amdgcn_global_load_lds(AS1C(A  + (size_t)(row0+m)*256 + (kt) + gs*8),  \
                                       AS3(&As[buf][qb*8]), 16, 0, 0);                 \
      __builtin_amdgcn_global_load_lds(AS1C(Bt + (size_t)(col0+m)*256 + (kt) + gs*8),  \
                                       AS3(&Bs[buf][qb*8]), 16, 0, 0);                 \
    }                                                                                  \
  }

  STAGE_AB(0, 0)
  asm volatile("s_waitcnt vmcnt(0)" ::: "memory");
  __syncthreads();

  for (int t=0; t<8; ++t) {
    int cur = t&1;
    if (t<7) STAGE_AB(cur^1, (t+1)*32)

    short8 af[2][2], bfr[2][2];
    #pragma unroll
    for (int fm=0; fm<2; ++fm)
      #pragma unroll
      for (int kh=0; kh<2; ++kh) {
        int row = wm*64 + fm*32 + l31;
        int sa  = (kh*2 + lh) ^ ((row>>1)&3);
        af[fm][kh] = *(const short8*)&As[cur][row*32 + sa*8];
      }
    #pragma unroll
    for (int fn=0; fn<2; ++fn)
      #pragma unroll
      for (int kh=0; kh<2; ++kh) {
        int col = wn*64 + fn*32 + l31;
        int sb  = (kh*2 + lh) ^ ((col>>1)&3);
        bfr[fn][kh] = *(const short8*)&Bs[cur][col*32 + sb*8];
      }
    #pragma unroll
    for (int kh=0; kh<2; ++kh)
      #pragma unroll
      for (int fm=0; fm<2; ++fm)
        #pragma unroll
        for (int fn=0; fn<2; ++fn)
          acc[fm][fn] = __builtin_amdgcn_mfma_f32_32x32x16_bf16(af[fm][kh], bfr[fn][kh], acc[fm][fn], 0, 0, 0);
    asm volatile("s_waitcnt vmcnt(0)" ::: "memory");
    __syncthreads();
  }
#undef STAGE_AB

  #pragma unroll
  for (int fn=0; fn<2; ++fn) {
    int col = col0 + wn*64 + fn*32 + l31;
    #pragma unroll
    for (int fm=0; fm<2; ++fm) {
      int rbase = row0 + wm*64 + fm*32 + 4*lh;
      #pragma unroll
      for (int reg=0; reg<16; ++reg) {
        int row = rbase + (reg&3) + 8*(reg>>2);
        C[(size_t)row*256 + col] = f2bf(acc[fm][fn][reg]);
      }
    }
  }
}

// ---------------- graph prep ----------------
__global__ void fill_all(const int* __restrict__ row, const int* __restrict__ col,
                         int* __restrict__ cur, int* __restrict__ bucket){
  int e = blockIdx.x*256 + threadIdx.x;
  if (e >= EEDG) return;
  int c = col[e];
  int s = atomicAdd(&cur[c], 1);
  if (s < CAP) bucket[(size_t)c*CAP + s] = row[e];
}
__global__ void calc_dinv(const int* __restrict__ cnt, float* __restrict__ dinv){
  int n = blockIdx.x*256 + threadIdx.x;
  if (n < NNODE) dinv[n] = rsqrtf((float)cnt[n] + 1.0f);
}

// ---------------- fused: aggregate + bg + GELU + residual + LN + head logits ----------------
__global__ __launch_bounds__(256) void fused_agg(
    const u16* __restrict__ xl, const u16* __restrict__ xhi,
    const int* __restrict__ cnt, const float* __restrict__ dinv, const int* __restrict__ bucket,
    const float* __restrict__ bgv, const float* __restrict__ gam, const float* __restrict__ bet,
    const float* __restrict__ qv, float* __restrict__ outg, float* __restrict__ logits)
{
  const int wid = threadIdx.x>>6, lane = threadIdx.x&63;
  const int half = lane>>5, sl = lane&31;
  const int n = blockIdx.x*8 + wid*2 + half;
  const int c0 = sl*8;
  const float dn = dinv[n];
  int lim = cnt[n]; if (lim > CAP) lim = CAP;

  int rl = bucket[(size_t)n*CAP + sl];
  if (sl >= lim) rl = n;                 // sanitize poison slots
  float wl = (sl < lim) ? dinv[rl]*dn : 0.0f;

  // residual x (independent -> issue early)
  float xv[8];
  uint4 qh = *(const uint4*)(xhi + (size_t)n*256 + c0);

  float a[8];
  {
    uint4 q = *(const uint4*)(xl + (size_t)n*256 + c0);
    unpack8(q, a);
    float wself = dn*dn;
    #pragma unroll
    for (int j=0;j<8;++j) a[j] *= wself;
  }

  int limR = (lim + 3) & ~3;
  for (int s=0; s<limR; s+=4) {
    int b0 = half*32 + s;
    int  r0 = __shfl(rl, b0),   r1 = __shfl(rl, b0+1);
    int  r2 = __shfl(rl, b0+2), r3 = __shfl(rl, b0+3);
    float w0 = __shfl(wl, b0),   w1 = __shfl(wl, b0+1);
    float w2 = __shfl(wl, b0+2), w3 = __shfl(wl, b0+3);
    uint4 q0 = *(const uint4*)(xl + (size_t)r0*256 + c0);
    uint4 q1 = *(const uint4*)(xl + (size_t)r1*256 + c0);
    uint4 q2 = *(const uint4*)(xl + (size_t)r2*256 + c0);
    uint4 q3 = *(const uint4*)(xl + (size_t)r3*256 + c0);
    float f0[8], f1[8], f2[8], f3[8];
    unpack8(q0, f0); unpack8(q1, f1); unpack8(q2, f2); unpack8(q3, f3);
    #pragma unroll
    for (int j=0;j<8;++j) a[j] += f0[j]*w0 + f1[j]*w1 + f2[j]*w2 + f3[j]*w3;
  }

  unpack8(qh, xv);

  float4 b0v = *(const float4*)(bgv + c0), b1v = *(const float4*)(bgv + c0 + 4);
  float bgs[8] = {b0v.x,b0v.y,b0v.z,b0v.w,b1v.x,b1v.y,b1v.z,b1v.w};
  float g[8];
  float s1 = 0.f, s2 = 0.f;
  #pragma unroll
  for (int j=0;j<8;++j){
    g[j] = gelu_exact(a[j] + bgs[j]) + xv[j];
    s1 += g[j]; s2 += g[j]*g[j];
  }
  #pragma unroll
  for (int off=16; off; off>>=1){ s1 += __shfl_xor(s1, off); s2 += __shfl_xor(s2, off); }
  float mu  = s1*(1.0f/256.0f);
  float var = s2*(1.0f/256.0f) - mu*mu;
  float inv = rsqrtf(var + 1e-5f);

  float4 g0 = *(const float4*)(gam + c0), g1 = *(const float4*)(gam + c0 + 4);
  float4 e0 = *(const float4*)(bet + c0), e1 = *(const float4*)(bet + c0 + 4);
  float gms[8] = {g0.x,g0.y,g0.z,g0.w,g1.x,g1.y,g1.z,g1.w};
  float bts[8] = {e0.x,e0.y,e0.z,e0.w,e1.x,e1.y,e1.z,e1.w};
  float y[8];
  #pragma unroll
  for (int j=0;j<8;++j) y[j] = (g[j]-mu)*inv*gms[j] + bts[j];

  f32x4 o0 = {y[0],y[1],y[2],y[3]}, o1 = {y[4],y[5],y[6],y[7]};
  __builtin_nontemporal_store(o0, (f32x4*)(outg + (size_t)n*256 + c0));
  __builtin_nontemporal_store(o1, (f32x4*)(outg + (size_t)n*256 + c0 + 4));

  float4 q0 = *(const float4*)(qv + c0), q1 = *(const float4*)(qv + c0 + 4);
  float qs[8] = {q0.x,q0.y,q0.z,q0.w,q1.x,q1.y,q1.z,q1.w};
  float dq = 0.f;
  #pragma unroll
  for (int j=0;j<8;++j) dq += y[j]*qs[j];
  dq += __shfl_xor(dq,1); dq += __shfl_xor(dq,2);
  if ((sl&3)==0){
    int b = n>>12, p = n&4095, h = sl>>2;
    logits[(size_t)(b*8+h)*4096 + p] = dq*10.0f;   // 1/TEMPERATURE
  }
}

// ---------------- row softmax over 4096 (fp32 in/out) ----------------
__global__ __launch_bounds__(256) void softmax_rows(const float* __restrict__ logits, float* __restrict__ outa){
  int r = blockIdx.x;
  const float* p = logits + (size_t)r*4096;
  int tid = threadIdx.x;
  int wid = tid>>6, lane = tid&63;
  __shared__ float redm[4];
  __shared__ float reds[4];
  float v[16];
  float mx = -1e30f;
  for (int i=0;i<16;++i){ v[i] = p[tid + i*256]; mx = fmaxf(mx, v[i]); }
  for (int off=32; off; off>>=1) mx = fmaxf(mx, __shfl_xor(mx, off));
  if (lane==0) redm[wid]=mx;
  __syncthreads();
  mx = fmaxf(fmaxf(redm[0],redm[1]), fmaxf(redm[2],redm[3]));
  float sum = 0.f;
  for (int i=0;i<16;++i){ v[i] = expf(v[i]-mx); sum += v[i]; }
  for (int off=32; off; off>>=1) sum += __shfl_xor(sum, off);
  if (lane==0) reds[wid]=sum;
  __syncthreads();
  sum = reds[0]+reds[1]+reds[2]+reds[3];
  float rinv = 1.0f/sum;
  for (int i=0;i<16;++i) outa[(size_t)r*4096 + tid + i*256] = v[i]*rinv;
}

extern "C" void kernel_launch(void* const* d_in, const int* in_sizes, int n_in,
                              void* d_out, int out_size, void* d_ws, size_t ws_size,
                              hipStream_t stream)
{
  const float* img  = (const float*)d_in[0];
  const int* edges  = (const int*)d_in[1];   // [2][E] int32: row=edges, col=edges+E
  const float* Wp   = (const float*)d_in[2];
  const float* bp   = (const float*)d_in[3];
  const float* Wg   = (const float*)d_in[4];
  const float* bg   = (const float*)d_in[5];
  const float* lng  = (const float*)d_in[6];
  const float* lnb  = (const float*)d_in[7];
  const float* dq   = (const float*)d_in[8];
  char* ws = (char*)d_ws;

  constexpr size_t REG  = (size_t)NNODE*CC*2;                                   // 67,108,864
  constexpr size_t WTS  = 2u*131072;
  constexpr size_t GBLK = 524288u*2 + (size_t)NNODE*CAP*4 + (size_t)256*4096*4; // ~21.8 MB
  if (ws_size < 2*REG + WTS + GBLK) return;

  u16* x_hi = (u16*)(ws + 0);
  u16* xl   = (u16*)(ws + REG);
  char* wts  = ws + 2*REG;
  char* gblk = wts + WTS;

  u16* WpT_hi = (u16*)(wts);
  u16* WgT_hi = (u16*)(wts + 131072);
  int*   cur    = (int*)(gblk);
  float* dinv   = (float*)(gblk + 524288);
  int*   bucket = (int*)(gblk + 1048576);
  float* logits = (float*)(gblk + 1048576 + (size_t)NNODE*CAP*4);

  // weight transposes (tiny, hi only)
  transpose_split<<<dim3(4,4,1), 256, 0, stream>>>(Wp, WpT_hi, nullptr, 256, 256, 0, 0);
  transpose_split<<<dim3(4,4,1), 256, 0, stream>>>(Wg, WgT_hi, nullptr, 256, 256, 0, 0);

  // graph prep
  hipMemsetAsync(cur, 0, 524288, stream);
  fill_all <<<2048, 256, 0, stream>>>(edges, edges+EEDG, cur, bucket);
  calc_dinv<<<512,  256, 0, stream>>>(cur, dinv);

  // x = imgT @ Wp + bp   (transpose fused into GEMM, 2-product split)
  gemm_img<<<dim3(1024,2), 256, 0, stream>>>(img, WpT_hi, bp, x_hi);
  // xl = x @ Wg          (1-product)
  gemm1p<<<dim3(1024,2), 256, 0, stream>>>(x_hi, WgT_hi, xl);

  float* outg = (float*)d_out;
  float* outa = (float*)d_out + (size_t)NNODE*CC;
  fused_agg<<<NNODE/8, 256, 0, stream>>>(xl, x_hi, cur, dinv, bucket,
                                         bg, lng, lnb, dq, outg, logits);
  softmax_rows<<<256, 256, 0, stream>>>(logits, outa);
}

// Round 7
// 237.020 us; speedup vs baseline: 1.7031x; 1.0232x over previous
//
#include <hip/hip_runtime.h>

typedef unsigned short u16;
typedef __attribute__((ext_vector_type(8))) short short8;
typedef __attribute__((ext_vector_type(4))) float f32x4;
typedef __attribute__((ext_vector_type(16))) float f32x16;

#define AS1C(p) ((const __attribute__((address_space(1))) void*)(p))
#define AS3(p)  ((__attribute__((address_space(3))) void*)(p))

constexpr int CC    = 256;      // channels
constexpr int HWSZ  = 4096;     // H*W
constexpr int NNODE = 131072;   // B*H*W
constexpr int EEDG  = 524288;   // edges
constexpr int CAP   = 32;       // per-node bucket capacity

__device__ __forceinline__ float bf2f(u16 h){ unsigned u = ((unsigned)h)<<16; float f; __builtin_memcpy(&f,&u,4); return f; }
__device__ __forceinline__ u16 f2bf(float f){ unsigned u; __builtin_memcpy(&u,&f,4); return (u16)((u + 0x7FFFu + ((u>>16)&1u))>>16); }
__device__ __forceinline__ float gelu_exact(float v){ return 0.5f*v*(1.0f + erff(v*0.7071067811865476f)); }

__device__ __forceinline__ void unpack8(uint4 q, float f[8]){
  unsigned w0=q.x,w1=q.y,w2=q.z,w3=q.w;
  unsigned l0=w0<<16, h0=w0&0xffff0000u, l1=w1<<16, h1=w1&0xffff0000u;
  unsigned l2=w2<<16, h2=w2&0xffff0000u, l3=w3<<16, h3=w3&0xffff0000u;
  __builtin_memcpy(&f[0],&l0,4); __builtin_memcpy(&f[1],&h0,4);
  __builtin_memcpy(&f[2],&l1,4); __builtin_memcpy(&f[3],&h1,4);
  __builtin_memcpy(&f[4],&l2,4); __builtin_memcpy(&f[5],&h2,4);
  __builtin_memcpy(&f[6],&l3,4); __builtin_memcpy(&f[7],&h3,4);
}

// ---------------- fp32 64x64 tiled transpose (weights; hi only used) ----------------
__global__ __launch_bounds__(256) void transpose_split(const float* __restrict__ src,
                                                       u16* __restrict__ dhi, u16* __restrict__ dlo,
                                                       int R, int Ccols, size_t sb_in, size_t sb_out)
{
  __shared__ float t[64][65];
  const float* s = src + blockIdx.z*sb_in + (size_t)(blockIdx.y*64)*Ccols + blockIdx.x*64;
  size_t obase   = blockIdx.z*sb_out + (size_t)(blockIdx.x*64)*R + blockIdx.y*64;
  int tid = threadIdx.x;
  for (int i=0;i<4;++i){
    int idx = i*256 + tid;
    int r = idx>>4, q = idx&15;
    float4 v = *(const float4*)(s + (size_t)r*Ccols + q*4);
    t[r][q*4+0]=v.x; t[r][q*4+1]=v.y; t[r][q*4+2]=v.z; t[r][q*4+3]=v.w;
  }
  __syncthreads();
  for (int i=0;i<2;++i){
    int idx = i*256 + tid;
    int rr = idx>>3, ch = idx&7;
    u16 hi[8], lo[8];
    for (int j=0;j<8;++j){
      float f = t[ch*8+j][rr];
      u16 h = f2bf(f); hi[j] = h;
      lo[j] = f2bf(f - bf2f(h));
    }
    *(uint4*)(dhi + obase + (size_t)rr*R + ch*8) = *(uint4*)hi;
    if (dlo) *(uint4*)(dlo + obase + (size_t)rr*R + ch*8) = *(uint4*)lo;
  }
}

// ---------------- GEMM1 (transpose-fused): x = imgT @ Wp + bp ----------------
// BM=64, BN=256 (4 waves x 64-col stripes) -> img read ONCE.
// A staged fp32 c-major [32][64] in LDS (bank = row%32, 2-way free);
// in-register truncation split -> 2-product 32x32x16 MFMA. 2-phase dbuf.
__global__ __launch_bounds__(256,2) void gemm_img(const float* __restrict__ img,
                                                  const u16* __restrict__ Bt,
                                                  const float* __restrict__ bias,
                                                  u16* __restrict__ C)
{
  __shared__ float Afp[2][32*64];
  __shared__ u16   Bs[2][256*32];
  const int tid = threadIdx.x, wid = tid>>6, lane = tid&63;
  const int row0 = blockIdx.x*64;
  const int bb = row0 >> 12, hw0 = row0 & 4095;
  const float* abase = img + (size_t)bb*CC*HWSZ + hw0;
  const int l31 = lane&31, lh = lane>>5;

  f32x16 acc[2][2];
  #pragma unroll
  for (int i=0;i<2;++i)
    #pragma unroll
    for (int j=0;j<2;++j)
      #pragma unroll
      for (int e=0;e<16;++e) acc[i][j][e]=0.f;

#define STAGE_IMG(buf, kt)                                                             \
  {                                                                                    \
    _Pragma("unroll")                                                                  \
    for (int it=0; it<2; ++it){                                                        \
      int qb = (it*4+wid)*64;                                                          \
      int q  = qb + lane;                                                              \
      int c  = q>>4, mq = q&15;                                                        \
      __builtin_amdgcn_global_load_lds(AS1C(abase + (size_t)((kt)+c)*HWSZ + mq*4),     \
                                       AS3(&Afp[buf][qb*4]), 16, 0, 0);                \
    }                                                                                  \
    _Pragma("unroll")                                                                  \
    for (int it=0; it<4; ++it){                                                        \
      int qb = (it*4+wid)*64;                                                          \
      int q  = qb + lane;                                                              \
      int m  = q>>2, sc = q&3;                                                         \
      int gs = sc ^ ((m>>1)&3);                                                        \
      __builtin_amdgcn_global_load_lds(AS1C(Bt + (size_t)m*256 + (kt) + gs*8),         \
                                       AS3(&Bs[buf][qb*8]), 16, 0, 0);                 \
    }                                                                                  \
  }

  STAGE_IMG(0, 0)
  asm volatile("s_waitcnt vmcnt(0)" ::: "memory");
  __syncthreads();

  for (int t=0; t<8; ++t) {
    int cur = t&1;
    if (t<7) STAGE_IMG(cur^1, (t+1)*32)

    short8 ah[2][2], al[2][2], bfr[2][2];
    #pragma unroll
    for (int fm=0; fm<2; ++fm)
      #pragma unroll
      for (int kh=0; kh<2; ++kh) {
        int r  = fm*32 + l31;
        int cb = kh*16 + lh*8;
        #pragma unroll
        for (int j=0; j<8; ++j) {
          float f = Afp[cur][(cb+j)*64 + r];
          unsigned u; __builtin_memcpy(&u,&f,4);
          ah[fm][kh][j] = (short)(u>>16);
          unsigned uh = u & 0xffff0000u;
          float fh; __builtin_memcpy(&fh,&uh,4);
          float fl = f - fh;
          unsigned ul; __builtin_memcpy(&ul,&fl,4);
          al[fm][kh][j] = (short)(ul>>16);
        }
      }
    #pragma unroll
    for (int fn=0; fn<2; ++fn)
      #pragma unroll
      for (int kh=0; kh<2; ++kh) {
        int col = wid*64 + fn*32 + l31;
        int sb  = (kh*2 + lh) ^ ((col>>1)&3);
        bfr[fn][kh] = *(const short8*)&Bs[cur][col*32 + sb*8];
      }
    #pragma unroll
    for (int kh=0; kh<2; ++kh)
      #pragma unroll
      for (int fm=0; fm<2; ++fm)
        #pragma unroll
        for (int fn=0; fn<2; ++fn) {
          acc[fm][fn] = __builtin_amdgcn_mfma_f32_32x32x16_bf16(ah[fm][kh], bfr[fn][kh], acc[fm][fn], 0, 0, 0);
          acc[fm][fn] = __builtin_amdgcn_mfma_f32_32x32x16_bf16(al[fm][kh], bfr[fn][kh], acc[fm][fn], 0, 0, 0);
        }
    asm volatile("s_waitcnt vmcnt(0)" ::: "memory");
    __syncthreads();
  }
#undef STAGE_IMG

  #pragma unroll
  for (int fn=0; fn<2; ++fn) {
    int col = wid*64 + fn*32 + l31;
    float bv = bias ? bias[col] : 0.f;
    #pragma unroll
    for (int fm=0; fm<2; ++fm) {
      int rbase = row0 + fm*32 + 4*lh;
      #pragma unroll
      for (int reg=0; reg<16; ++reg) {
        int row = rbase + (reg&3) + 8*(reg>>2);
        C[(size_t)row*256 + col] = f2bf(acc[fm][fn][reg] + bv);
      }
    }
  }
}

// ---------------- GEMM2: xl = x @ Wg  (BM=64, BN=256, 1-product) ----------------
__global__ __launch_bounds__(256,2) void gemm1p(const u16* __restrict__ A,
                                                const u16* __restrict__ Bt,
                                                u16* __restrict__ C)
{
  __shared__ u16 As[2][64*32];
  __shared__ u16 Bs[2][256*32];
  const int tid = threadIdx.x, wid = tid>>6, lane = tid&63;
  const int row0 = blockIdx.x*64;
  const int l31 = lane&31, lh = lane>>5;

  f32x16 acc[2][2];
  #pragma unroll
  for (int i=0;i<2;++i)
    #pragma unroll
    for (int j=0;j<2;++j)
      #pragma unroll
      for (int e=0;e<16;++e) acc[i][j][e]=0.f;

#define STAGE_AB(buf, kt)                                                              \
  {                                                                                    \
    {                                                                                  \
      int qb = wid*64;                                                                 \
      int q  = qb + lane;                                                              \
      int m  = q>>2, sc = q&3;                                                         \
      int gs = sc ^ ((m>>1)&3);                                                        \
      __builtin_amdgcn_global_load_lds(AS1C(A + (size_t)(row0+m)*256 + (kt) + gs*8),   \
                                       AS3(&As[buf][qb*8]), 16, 0, 0);                 \
    }                                                                                  \
    _Pragma("unroll")                                                                  \
    for (int it=0; it<4; ++it){                                                        \
      int qb = (it*4+wid)*64;                                                          \
      int q  = qb + lane;                                                              \
      int m  = q>>2, sc = q&3;                                                         \
      int gs = sc ^ ((m>>1)&3);                                                        \
      __builtin_amdgcn_global_load_lds(AS1C(Bt + (size_t)m*256 + (kt) + gs*8),         \
                                       AS3(&Bs[buf][qb*8]), 16, 0, 0);                 \
    }                                                                                  \
  }

  STAGE_AB(0, 0)
  asm volatile("s_waitcnt vmcnt(0)" ::: "memory");
  __syncthreads();

  for (int t=0; t<8; ++t) {
    int cur = t&1;
    if (t<7) STAGE_AB(cur^1, (t+1)*32)

    short8 af[2][2], bfr[2][2];
    #pragma unroll
    for (int fm=0; fm<2; ++fm)
      #pragma unroll
      for (int kh=0; kh<2; ++kh) {
        int row = fm*32 + l31;
        int sa  = (kh*2 + lh) ^ ((row>>1)&3);
        af[fm][kh] = *(const short8*)&As[cur][row*32 + sa*8];
      }
    #pragma unroll
    for (int fn=0; fn<2; ++fn)
      #pragma unroll
      for (int kh=0; kh<2; ++kh) {
        int col = wid*64 + fn*32 + l31;
        int sb  = (kh*2 + lh) ^ ((col>>1)&3);
        bfr[fn][kh] = *(const short8*)&Bs[cur][col*32 + sb*8];
      }
    #pragma unroll
    for (int kh=0; kh<2; ++kh)
      #pragma unroll
      for (int fm=0; fm<2; ++fm)
        #pragma unroll
        for (int fn=0; fn<2; ++fn)
          acc[fm][fn] = __builtin_amdgcn_mfma_f32_32x32x16_bf16(af[fm][kh], bfr[fn][kh], acc[fm][fn], 0, 0, 0);
    asm volatile("s_waitcnt vmcnt(0)" ::: "memory");
    __syncthreads();
  }
#undef STAGE_AB

  #pragma unroll
  for (int fn=0; fn<2; ++fn) {
    int col = wid*64 + fn*32 + l31;
    #pragma unroll
    for (int fm=0; fm<2; ++fm) {
      int rbase = row0 + fm*32 + 4*lh;
      #pragma unroll
      for (int reg=0; reg<16; ++reg) {
        int row = rbase + (reg&3) + 8*(reg>>2);
        C[(size_t)row*256 + col] = f2bf(acc[fm][fn][reg]);
      }
    }
  }
}

// ---------------- graph prep ----------------
__global__ void fill_all(const int* __restrict__ row, const int* __restrict__ col,
                         int* __restrict__ cur, int* __restrict__ bucket){
  int e = blockIdx.x*256 + threadIdx.x;
  if (e >= EEDG) return;
  int c = col[e];
  int s = atomicAdd(&cur[c], 1);
  if (s < CAP) bucket[(size_t)c*CAP + s] = row[e];
}
__global__ void calc_dinv(const int* __restrict__ cnt, float* __restrict__ dinv){
  int n = blockIdx.x*256 + threadIdx.x;
  if (n < NNODE) dinv[n] = rsqrtf((float)cnt[n] + 1.0f);
}

// ---------------- fused: aggregate + bg + GELU + residual + LN + head logits ----------------
__global__ __launch_bounds__(256) void fused_agg(
    const u16* __restrict__ xl, const u16* __restrict__ xhi,
    const int* __restrict__ cnt, const float* __restrict__ dinv, const int* __restrict__ bucket,
    const float* __restrict__ bgv, const float* __restrict__ gam, const float* __restrict__ bet,
    const float* __restrict__ qv, float* __restrict__ outg, float* __restrict__ logits)
{
  const int wid = threadIdx.x>>6, lane = threadIdx.x&63;
  const int half = lane>>5, sl = lane&31;
  const int n = blockIdx.x*8 + wid*2 + half;
  const int c0 = sl*8;
  const float dn = dinv[n];
  int lim = cnt[n]; if (lim > CAP) lim = CAP;

  int rl = bucket[(size_t)n*CAP + sl];
  if (sl >= lim) rl = n;                 // sanitize poison slots
  float wl = (sl < lim) ? dinv[rl]*dn : 0.0f;

  // residual x (independent -> issue early)
  uint4 qh = *(const uint4*)(xhi + (size_t)n*256 + c0);

  float a[8];
  {
    uint4 q = *(const uint4*)(xl + (size_t)n*256 + c0);
    unpack8(q, a);
    float wself = dn*dn;
    #pragma unroll
    for (int j=0;j<8;++j) a[j] *= wself;
  }

  int limR = (lim + 3) & ~3;
  for (int s=0; s<limR; s+=4) {
    int b0 = half*32 + s;
    int  r0 = __shfl(rl, b0),   r1 = __shfl(rl, b0+1);
    int  r2 = __shfl(rl, b0+2), r3 = __shfl(rl, b0+3);
    float w0 = __shfl(wl, b0),   w1 = __shfl(wl, b0+1);
    float w2 = __shfl(wl, b0+2), w3 = __shfl(wl, b0+3);
    uint4 q0 = *(const uint4*)(xl + (size_t)r0*256 + c0);
    uint4 q1 = *(const uint4*)(xl + (size_t)r1*256 + c0);
    uint4 q2 = *(const uint4*)(xl + (size_t)r2*256 + c0);
    uint4 q3 = *(const uint4*)(xl + (size_t)r3*256 + c0);
    float f0[8], f1[8], f2[8], f3[8];
    unpack8(q0, f0); unpack8(q1, f1); unpack8(q2, f2); unpack8(q3, f3);
    #pragma unroll
    for (int j=0;j<8;++j) a[j] += f0[j]*w0 + f1[j]*w1 + f2[j]*w2 + f3[j]*w3;
  }

  float xv[8];
  unpack8(qh, xv);

  float4 b0v = *(const float4*)(bgv + c0), b1v = *(const float4*)(bgv + c0 + 4);
  float bgs[8] = {b0v.x,b0v.y,b0v.z,b0v.w,b1v.x,b1v.y,b1v.z,b1v.w};
  float g[8];
  float s1 = 0.f, s2 = 0.f;
  #pragma unroll
  for (int j=0;j<8;++j){
    g[j] = gelu_exact(a[j] + bgs[j]) + xv[j];
    s1 += g[j]; s2 += g[j]*g[j];
  }
  #pragma unroll
  for (int off=16; off; off>>=1){ s1 += __shfl_xor(s1, off); s2 += __shfl_xor(s2, off); }
  float mu  = s1*(1.0f/256.0f);
  float var = s2*(1.0f/256.0f) - mu*mu;
  float inv = rsqrtf(var + 1e-5f);

  float4 g0 = *(const float4*)(gam + c0), g1 = *(const float4*)(gam + c0 + 4);
  float4 e0 = *(const float4*)(bet + c0), e1 = *(const float4*)(bet + c0 + 4);
  float gms[8] = {g0.x,g0.y,g0.z,g0.w,g1.x,g1.y,g1.z,g1.w};
  float bts[8] = {e0.x,e0.y,e0.z,e0.w,e1.x,e1.y,e1.z,e1.w};
  float y[8];
  #pragma unroll
  for (int j=0;j<8;++j) y[j] = (g[j]-mu)*inv*gms[j] + bts[j];

  float4 o0 = {y[0],y[1],y[2],y[3]}, o1 = {y[4],y[5],y[6],y[7]};
  *reinterpret_cast<float4*>(outg + (size_t)n*256 + c0)     = o0;
  *reinterpret_cast<float4*>(outg + (size_t)n*256 + c0 + 4) = o1;

  float4 q0 = *(const float4*)(qv + c0), q1 = *(const float4*)(qv + c0 + 4);
  float qs[8] = {q0.x,q0.y,q0.z,q0.w,q1.x,q1.y,q1.z,q1.w};
  float dq = 0.f;
  #pragma unroll
  for (int j=0;j<8;++j) dq += y[j]*qs[j];
  dq += __shfl_xor(dq,1); dq += __shfl_xor(dq,2);
  if ((sl&3)==0){
    int b = n>>12, p = n&4095, h = sl>>2;
    logits[(size_t)(b*8+h)*4096 + p] = dq*10.0f;   // 1/TEMPERATURE
  }
}

// ---------------- row softmax over 4096 (fp32 in/out) ----------------
__global__ __launch_bounds__(256) void softmax_rows(const float* __restrict__ logits, float* __restrict__ outa){
  int r = blockIdx.x;
  const float* p = logits + (size_t)r*4096;
  int tid = threadIdx.x;
  int wid = tid>>6, lane = tid&63;
  __shared__ float redm[4];
  __shared__ float reds[4];
  float v[16];
  float mx = -1e30f;
  for (int i=0;i<16;++i){ v[i] = p[tid + i*256]; mx = fmaxf(mx, v[i]); }
  for (int off=32; off; off>>=1) mx = fmaxf(mx, __shfl_xor(mx, off));
  if (lane==0) redm[wid]=mx;
  __syncthreads();
  mx = fmaxf(fmaxf(redm[0],redm[1]), fmaxf(redm[2],redm[3]));
  float sum = 0.f;
  for (int i=0;i<16;++i){ v[i] = expf(v[i]-mx); sum += v[i]; }
  for (int off=32; off; off>>=1) sum += __shfl_xor(sum, off);
  if (lane==0) reds[wid]=sum;
  __syncthreads();
  sum = reds[0]+reds[1]+reds[2]+reds[3];
  float rinv = 1.0f/sum;
  for (int i=0;i<16;++i) outa[(size_t)r*4096 + tid + i*256] = v[i]*rinv;
}

extern "C" void kernel_launch(void* const* d_in, const int* in_sizes, int n_in,
                              void* d_out, int out_size, void* d_ws, size_t ws_size,
                              hipStream_t stream)
{
  const float* img  = (const float*)d_in[0];
  const int* edges  = (const int*)d_in[1];   // [2][E] int32: row=edges, col=edges+E
  const float* Wp   = (const float*)d_in[2];
  const float* bp   = (const float*)d_in[3];
  const float* Wg   = (const float*)d_in[4];
  const float* bg   = (const float*)d_in[5];
  const float* lng  = (const float*)d_in[6];
  const float* lnb  = (const float*)d_in[7];
  const float* dq   = (const float*)d_in[8];
  char* ws = (char*)d_ws;

  constexpr size_t REG  = (size_t)NNODE*CC*2;                                   // 67,108,864
  constexpr size_t WTS  = 2u*131072;
  constexpr size_t GBLK = 524288u*2 + (size_t)NNODE*CAP*4 + (size_t)256*4096*4; // ~21.8 MB
  if (ws_size < 2*REG + WTS + GBLK) return;

  u16* x_hi = (u16*)(ws + 0);
  u16* xl   = (u16*)(ws + REG);
  char* wts  = ws + 2*REG;
  char* gblk = wts + WTS;

  u16* WpT_hi = (u16*)(wts);
  u16* WgT_hi = (u16*)(wts + 131072);
  int*   cur    = (int*)(gblk);
  float* dinv   = (float*)(gblk + 524288);
  int*   bucket = (int*)(gblk + 1048576);
  float* logits = (float*)(gblk + 1048576 + (size_t)NNODE*CAP*4);

  // weight transposes (tiny, hi only)
  transpose_split<<<dim3(4,4,1), 256, 0, stream>>>(Wp, WpT_hi, nullptr, 256, 256, 0, 0);
  transpose_split<<<dim3(4,4,1), 256, 0, stream>>>(Wg, WgT_hi, nullptr, 256, 256, 0, 0);

  // graph prep
  hipMemsetAsync(cur, 0, 524288, stream);
  fill_all <<<2048, 256, 0, stream>>>(edges, edges+EEDG, cur, bucket);
  calc_dinv<<<512,  256, 0, stream>>>(cur, dinv);

  // x = imgT @ Wp + bp   (transpose fused, img read once, 2-product split)
  gemm_img<<<2048, 256, 0, stream>>>(img, WpT_hi, bp, x_hi);
  // xl = x @ Wg          (x read once, 1-product)
  gemm1p<<<2048, 256, 0, stream>>>(x_hi, WgT_hi, xl);

  float* outg = (float*)d_out;
  float* outa = (float*)d_out + (size_t)NNODE*CC;
  fused_agg<<<NNODE/8, 256, 0, stream>>>(xl, x_hi, cur, dinv, bucket,
                                         bg, lng, lnb, dq, outg, logits);
  softmax_rows<<<256, 256, 0, stream>>>(logits, outa);
}

// Round 8
// 233.282 us; speedup vs baseline: 1.7304x; 1.0160x over previous
//
#include <hip/hip_runtime.h>

typedef unsigned short u16;
typedef __attribute__((ext_vector_type(8))) short short8;
typedef __attribute__((ext_vector_type(4))) float f32x4;
typedef __attribute__((ext_vector_type(16))) float f32x16;

#define AS1C(p) ((const __attribute__((address_space(1))) void*)(p))
#define AS3(p)  ((__attribute__((address_space(3))) void*)(p))

constexpr int CC    = 256;      // channels
constexpr int HWSZ  = 4096;     // H*W
constexpr int NNODE = 131072;   // B*H*W
constexpr int EEDG  = 524288;   // edges
constexpr int CAP   = 32;       // per-node bucket capacity

__device__ __forceinline__ float bf2f(u16 h){ unsigned u = ((unsigned)h)<<16; float f; __builtin_memcpy(&f,&u,4); return f; }
__device__ __forceinline__ u16 f2bf(float f){ unsigned u; __builtin_memcpy(&u,&f,4); return (u16)((u + 0x7FFFu + ((u>>16)&1u))>>16); }

// tanh-form GELU via native exp (max abs err vs exact ~3e-4)
__device__ __forceinline__ float gelu_fast(float v){
  float y = 0.7978845608f*(v + 0.044715f*v*v*v);
  float e = __expf(2.0f*y);                       // v_exp_f32
  float r = __builtin_amdgcn_rcpf(e + 1.0f);      // v_rcp_f32
  return 0.5f*v*(2.0f - 2.0f*r) + 0.0f*v;         // 0.5v(1+t), t=1-2r
}

__device__ __forceinline__ void unpack8(uint4 q, float f[8]){
  unsigned w0=q.x,w1=q.y,w2=q.z,w3=q.w;
  unsigned l0=w0<<16, h0=w0&0xffff0000u, l1=w1<<16, h1=w1&0xffff0000u;
  unsigned l2=w2<<16, h2=w2&0xffff0000u, l3=w3<<16, h3=w3&0xffff0000u;
  __builtin_memcpy(&f[0],&l0,4); __builtin_memcpy(&f[1],&h0,4);
  __builtin_memcpy(&f[2],&l1,4); __builtin_memcpy(&f[3],&h1,4);
  __builtin_memcpy(&f[4],&l2,4); __builtin_memcpy(&f[5],&h2,4);
  __builtin_memcpy(&f[6],&l3,4); __builtin_memcpy(&f[7],&h3,4);
}

// ---------------- fp32 64x64 tiled transpose (weights; hi only used) ----------------
__global__ __launch_bounds__(256) void transpose_split(const float* __restrict__ src,
                                                       u16* __restrict__ dhi, u16* __restrict__ dlo,
                                                       int R, int Ccols, size_t sb_in, size_t sb_out)
{
  __shared__ float t[64][65];
  const float* s = src + blockIdx.z*sb_in + (size_t)(blockIdx.y*64)*Ccols + blockIdx.x*64;
  size_t obase   = blockIdx.z*sb_out + (size_t)(blockIdx.x*64)*R + blockIdx.y*64;
  int tid = threadIdx.x;
  for (int i=0;i<4;++i){
    int idx = i*256 + tid;
    int r = idx>>4, q = idx&15;
    float4 v = *(const float4*)(s + (size_t)r*Ccols + q*4);
    t[r][q*4+0]=v.x; t[r][q*4+1]=v.y; t[r][q*4+2]=v.z; t[r][q*4+3]=v.w;
  }
  __syncthreads();
  for (int i=0;i<2;++i){
    int idx = i*256 + tid;
    int rr = idx>>3, ch = idx&7;
    u16 hi[8], lo[8];
    for (int j=0;j<8;++j){
      float f = t[ch*8+j][rr];
      u16 h = f2bf(f); hi[j] = h;
      lo[j] = f2bf(f - bf2f(h));
    }
    *(uint4*)(dhi + obase + (size_t)rr*R + ch*8) = *(uint4*)hi;
    if (dlo) *(uint4*)(dlo + obase + (size_t)rr*R + ch*8) = *(uint4*)lo;
  }
}

// ---------------- GEMM1 (transpose-fused): x = imgT @ Wp + bp ----------------
// BM=64, BN=256 (4 waves x 64-col stripes) -> img read ONCE.
// A staged fp32 c-major [32][64] in LDS; fragments built by ds_read + v_perm
// truncation-pack (1-product bf16: x is consumed only as bf16 downstream, so
// the dropped img_lo term is below x's own bf16 quantization). 2-phase dbuf.
__global__ __launch_bounds__(256,2) void gemm_img(const float* __restrict__ img,
                                                  const u16* __restrict__ Bt,
                                                  const float* __restrict__ bias,
                                                  u16* __restrict__ C)
{
  __shared__ float Afp[2][32*64];
  __shared__ u16   Bs[2][256*32];
  const int tid = threadIdx.x, wid = tid>>6, lane = tid&63;
  const int row0 = blockIdx.x*64;
  const int bb = row0 >> 12, hw0 = row0 & 4095;
  const float* abase = img + (size_t)bb*CC*HWSZ + hw0;
  const int l31 = lane&31, lh = lane>>5;

  f32x16 acc[2][2];
  #pragma unroll
  for (int i=0;i<2;++i)
    #pragma unroll
    for (int j=0;j<2;++j)
      #pragma unroll
      for (int e=0;e<16;++e) acc[i][j][e]=0.f;

#define STAGE_IMG(buf, kt)                                                             \
  {                                                                                    \
    _Pragma("unroll")                                                                  \
    for (int it=0; it<2; ++it){                                                        \
      int qb = (it*4+wid)*64;                                                          \
      int q  = qb + lane;                                                              \
      int c  = q>>4, mq = q&15;                                                        \
      __builtin_amdgcn_global_load_lds(AS1C(abase + (size_t)((kt)+c)*HWSZ + mq*4),     \
                                       AS3(&Afp[buf][qb*4]), 16, 0, 0);                \
    }                                                                                  \
    _Pragma("unroll")                                                                  \
    for (int it=0; it<4; ++it){                                                        \
      int qb = (it*4+wid)*64;                                                          \
      int q  = qb + lane;                                                              \
      int m  = q>>2, sc = q&3;                                                         \
      int gs = sc ^ ((m>>1)&3);                                                        \
      __builtin_amdgcn_global_load_lds(AS1C(Bt + (size_t)m*256 + (kt) + gs*8),         \
                                       AS3(&Bs[buf][qb*8]), 16, 0, 0);                 \
    }                                                                                  \
  }

  STAGE_IMG(0, 0)
  asm volatile("s_waitcnt vmcnt(0)" ::: "memory");
  __syncthreads();

  for (int t=0; t<8; ++t) {
    int cur = t&1;
    if (t<7) STAGE_IMG(cur^1, (t+1)*32)

    short8 ah[2][2], bfr[2][2];
    #pragma unroll
    for (int fm=0; fm<2; ++fm)
      #pragma unroll
      for (int kh=0; kh<2; ++kh) {
        int r  = fm*32 + l31;
        int cb = kh*16 + lh*8;
        unsigned w[4];
        #pragma unroll
        for (int p=0; p<4; ++p) {
          unsigned u0, u1;
          float f0 = Afp[cur][(cb+2*p  )*64 + r];
          float f1 = Afp[cur][(cb+2*p+1)*64 + r];
          __builtin_memcpy(&u0,&f0,4); __builtin_memcpy(&u1,&f1,4);
          w[p] = __builtin_amdgcn_perm(u1, u0, 0x07060302u);  // [u0.hi16, u1.hi16]
        }
        __builtin_memcpy(&ah[fm][kh], w, 16);
      }
    #pragma unroll
    for (int fn=0; fn<2; ++fn)
      #pragma unroll
      for (int kh=0; kh<2; ++kh) {
        int col = wid*64 + fn*32 + l31;
        int sb  = (kh*2 + lh) ^ ((col>>1)&3);
        bfr[fn][kh] = *(const short8*)&Bs[cur][col*32 + sb*8];
      }
    #pragma unroll
    for (int kh=0; kh<2; ++kh)
      #pragma unroll
      for (int fm=0; fm<2; ++fm)
        #pragma unroll
        for (int fn=0; fn<2; ++fn)
          acc[fm][fn] = __builtin_amdgcn_mfma_f32_32x32x16_bf16(ah[fm][kh], bfr[fn][kh], acc[fm][fn], 0, 0, 0);
    asm volatile("s_waitcnt vmcnt(0)" ::: "memory");
    __syncthreads();
  }
#undef STAGE_IMG

  #pragma unroll
  for (int fn=0; fn<2; ++fn) {
    int col = wid*64 + fn*32 + l31;
    float bv = bias ? bias[col] : 0.f;
    #pragma unroll
    for (int fm=0; fm<2; ++fm) {
      int rbase = row0 + fm*32 + 4*lh;
      #pragma unroll
      for (int reg=0; reg<16; ++reg) {
        int row = rbase + (reg&3) + 8*(reg>>2);
        C[(size_t)row*256 + col] = f2bf(acc[fm][fn][reg] + bv);
      }
    }
  }
}

// ---------------- GEMM2: xl = x @ Wg  (BM=64, BN=256, 1-product) ----------------
__global__ __launch_bounds__(256,2) void gemm1p(const u16* __restrict__ A,
                                                const u16* __restrict__ Bt,
                                                u16* __restrict__ C)
{
  __shared__ u16 As[2][64*32];
  __shared__ u16 Bs[2][256*32];
  const int tid = threadIdx.x, wid = tid>>6, lane = tid&63;
  const int row0 = blockIdx.x*64;
  const int l31 = lane&31, lh = lane>>5;

  f32x16 acc[2][2];
  #pragma unroll
  for (int i=0;i<2;++i)
    #pragma unroll
    for (int j=0;j<2;++j)
      #pragma unroll
      for (int e=0;e<16;++e) acc[i][j][e]=0.f;

#define STAGE_AB(buf, kt)                                                              \
  {                                                                                    \
    {                                                                                  \
      int qb = wid*64;                                                                 \
      int q  = qb + lane;                                                              \
      int m  = q>>2, sc = q&3;                                                         \
      int gs = sc ^ ((m>>1)&3);                                                        \
      __builtin_amdgcn_global_load_lds(AS1C(A + (size_t)(row0+m)*256 + (kt) + gs*8),   \
                                       AS3(&As[buf][qb*8]), 16, 0, 0);                 \
    }                                                                                  \
    _Pragma("unroll")                                                                  \
    for (int it=0; it<4; ++it){                                                        \
      int qb = (it*4+wid)*64;                                                          \
      int q  = qb + lane;                                                              \
      int m  = q>>2, sc = q&3;                                                         \
      int gs = sc ^ ((m>>1)&3);                                                        \
      __builtin_amdgcn_global_load_lds(AS1C(Bt + (size_t)m*256 + (kt) + gs*8),         \
                                       AS3(&Bs[buf][qb*8]), 16, 0, 0);                 \
    }                                                                                  \
  }

  STAGE_AB(0, 0)
  asm volatile("s_waitcnt vmcnt(0)" ::: "memory");
  __syncthreads();

  for (int t=0; t<8; ++t) {
    int cur = t&1;
    if (t<7) STAGE_AB(cur^1, (t+1)*32)

    short8 af[2][2], bfr[2][2];
    #pragma unroll
    for (int fm=0; fm<2; ++fm)
      #pragma unroll
      for (int kh=0; kh<2; ++kh) {
        int row = fm*32 + l31;
        int sa  = (kh*2 + lh) ^ ((row>>1)&3);
        af[fm][kh] = *(const short8*)&As[cur][row*32 + sa*8];
      }
    #pragma unroll
    for (int fn=0; fn<2; ++fn)
      #pragma unroll
      for (int kh=0; kh<2; ++kh) {
        int col = wid*64 + fn*32 + l31;
        int sb  = (kh*2 + lh) ^ ((col>>1)&3);
        bfr[fn][kh] = *(const short8*)&Bs[cur][col*32 + sb*8];
      }
    #pragma unroll
    for (int kh=0; kh<2; ++kh)
      #pragma unroll
      for (int fm=0; fm<2; ++fm)
        #pragma unroll
        for (int fn=0; fn<2; ++fn)
          acc[fm][fn] = __builtin_amdgcn_mfma_f32_32x32x16_bf16(af[fm][kh], bfr[fn][kh], acc[fm][fn], 0, 0, 0);
    asm volatile("s_waitcnt vmcnt(0)" ::: "memory");
    __syncthreads();
  }
#undef STAGE_AB

  #pragma unroll
  for (int fn=0; fn<2; ++fn) {
    int col = wid*64 + fn*32 + l31;
    #pragma unroll
    for (int fm=0; fm<2; ++fm) {
      int rbase = row0 + fm*32 + 4*lh;
      #pragma unroll
      for (int reg=0; reg<16; ++reg) {
        int row = rbase + (reg&3) + 8*(reg>>2);
        C[(size_t)row*256 + col] = f2bf(acc[fm][fn][reg]);
      }
    }
  }
}

// ---------------- graph prep ----------------
__global__ void fill_all(const int* __restrict__ row, const int* __restrict__ col,
                         int* __restrict__ cur, int* __restrict__ bucket){
  int e = blockIdx.x*256 + threadIdx.x;
  if (e >= EEDG) return;
  int c = col[e];
  int s = atomicAdd(&cur[c], 1);
  if (s < CAP) bucket[(size_t)c*CAP + s] = row[e];
}
__global__ void calc_dinv(const int* __restrict__ cnt, float* __restrict__ dinv){
  int n = blockIdx.x*256 + threadIdx.x;
  if (n < NNODE) dinv[n] = rsqrtf((float)cnt[n] + 1.0f);
}

// ---------------- fused: aggregate + bg + GELU + residual + LN + head logits ----------------
__global__ __launch_bounds__(256) void fused_agg(
    const u16* __restrict__ xl, const u16* __restrict__ xhi,
    const int* __restrict__ cnt, const float* __restrict__ dinv, const int* __restrict__ bucket,
    const float* __restrict__ bgv, const float* __restrict__ gam, const float* __restrict__ bet,
    const float* __restrict__ qv, float* __restrict__ outg, float* __restrict__ logits)
{
  const int wid = threadIdx.x>>6, lane = threadIdx.x&63;
  const int half = lane>>5, sl = lane&31;
  const int n = blockIdx.x*8 + wid*2 + half;
  const int c0 = sl*8;
  const float dn = dinv[n];
  int lim = cnt[n]; if (lim > CAP) lim = CAP;

  int rl = bucket[(size_t)n*CAP + sl];
  if (sl >= lim) rl = n;                 // sanitize poison slots
  float wl = (sl < lim) ? dinv[rl]*dn : 0.0f;

  // residual x (independent -> issue early)
  uint4 qh = *(const uint4*)(xhi + (size_t)n*256 + c0);

  float a[8];
  {
    uint4 q = *(const uint4*)(xl + (size_t)n*256 + c0);
    unpack8(q, a);
    float wself = dn*dn;
    #pragma unroll
    for (int j=0;j<8;++j) a[j] *= wself;
  }

  int limR = (lim + 3) & ~3;
  for (int s=0; s<limR; s+=4) {
    int b0 = half*32 + s;
    int  r0 = __shfl(rl, b0),   r1 = __shfl(rl, b0+1);
    int  r2 = __shfl(rl, b0+2), r3 = __shfl(rl, b0+3);
    float w0 = __shfl(wl, b0),   w1 = __shfl(wl, b0+1);
    float w2 = __shfl(wl, b0+2), w3 = __shfl(wl, b0+3);
    uint4 q0 = *(const uint4*)(xl + (size_t)r0*256 + c0);
    uint4 q1 = *(const uint4*)(xl + (size_t)r1*256 + c0);
    uint4 q2 = *(const uint4*)(xl + (size_t)r2*256 + c0);
    uint4 q3 = *(const uint4*)(xl + (size_t)r3*256 + c0);
    float f0[8], f1[8], f2[8], f3[8];
    unpack8(q0, f0); unpack8(q1, f1); unpack8(q2, f2); unpack8(q3, f3);
    #pragma unroll
    for (int j=0;j<8;++j) a[j] += f0[j]*w0 + f1[j]*w1 + f2[j]*w2 + f3[j]*w3;
  }

  float xv[8];
  unpack8(qh, xv);

  float4 b0v = *(const float4*)(bgv + c0), b1v = *(const float4*)(bgv + c0 + 4);
  float bgs[8] = {b0v.x,b0v.y,b0v.z,b0v.w,b1v.x,b1v.y,b1v.z,b1v.w};
  float g[8];
  float s1 = 0.f, s2 = 0.f;
  #pragma unroll
  for (int j=0;j<8;++j){
    g[j] = gelu_fast(a[j] + bgs[j]) + xv[j];
    s1 += g[j]; s2 += g[j]*g[j];
  }
  #pragma unroll
  for (int off=16; off; off>>=1){ s1 += __shfl_xor(s1, off); s2 += __shfl_xor(s2, off); }
  float mu  = s1*(1.0f/256.0f);
  float var = s2*(1.0f/256.0f) - mu*mu;
  float inv = rsqrtf(var + 1e-5f);

  float4 g0 = *(const float4*)(gam + c0), g1 = *(const float4*)(gam + c0 + 4);
  float4 e0 = *(const float4*)(bet + c0), e1 = *(const float4*)(bet + c0 + 4);
  float gms[8] = {g0.x,g0.y,g0.z,g0.w,g1.x,g1.y,g1.z,g1.w};
  float bts[8] = {e0.x,e0.y,e0.z,e0.w,e1.x,e1.y,e1.z,e1.w};
  float y[8];
  #pragma unroll
  for (int j=0;j<8;++j) y[j] = (g[j]-mu)*inv*gms[j] + bts[j];

  float4 o0 = {y[0],y[1],y[2],y[3]}, o1 = {y[4],y[5],y[6],y[7]};
  *reinterpret_cast<float4*>(outg + (size_t)n*256 + c0)     = o0;
  *reinterpret_cast<float4*>(outg + (size_t)n*256 + c0 + 4) = o1;

  float4 q0 = *(const float4*)(qv + c0), q1 = *(const float4*)(qv + c0 + 4);
  float qs[8] = {q0.x,q0.y,q0.z,q0.w,q1.x,q1.y,q1.z,q1.w};
  float dq = 0.f;
  #pragma unroll
  for (int j=0;j<8;++j) dq += y[j]*qs[j];
  dq += __shfl_xor(dq,1); dq += __shfl_xor(dq,2);
  if ((sl&3)==0){
    int b = n>>12, p = n&4095, h = sl>>2;
    logits[(size_t)(b*8+h)*4096 + p] = dq*10.0f;   // 1/TEMPERATURE
  }
}

// ---------------- row softmax over 4096 (fp32 in/out) ----------------
__global__ __launch_bounds__(256) void softmax_rows(const float* __restrict__ logits, float* __restrict__ outa){
  int r = blockIdx.x;
  const float* p = logits + (size_t)r*4096;
  int tid = threadIdx.x;
  int wid = tid>>6, lane = tid&63;
  __shared__ float redm[4];
  __shared__ float reds[4];
  float v[16];
  float mx = -1e30f;
  for (int i=0;i<16;++i){ v[i] = p[tid + i*256]; mx = fmaxf(mx, v[i]); }
  for (int off=32; off; off>>=1) mx = fmaxf(mx, __shfl_xor(mx, off));
  if (lane==0) redm[wid]=mx;
  __syncthreads();
  mx = fmaxf(fmaxf(redm[0],redm[1]), fmaxf(redm[2],redm[3]));
  float sum = 0.f;
  for (int i=0;i<16;++i){ v[i] = expf(v[i]-mx); sum += v[i]; }
  for (int off=32; off; off>>=1) sum += __shfl_xor(sum, off);
  if (lane==0) reds[wid]=sum;
  __syncthreads();
  sum = reds[0]+reds[1]+reds[2]+reds[3];
  float rinv = 1.0f/sum;
  for (int i=0;i<16;++i) outa[(size_t)r*4096 + tid + i*256] = v[i]*rinv;
}

extern "C" void kernel_launch(void* const* d_in, const int* in_sizes, int n_in,
                              void* d_out, int out_size, void* d_ws, size_t ws_size,
                              hipStream_t stream)
{
  const float* img  = (const float*)d_in[0];
  const int* edges  = (const int*)d_in[1];   // [2][E] int32: row=edges, col=edges+E
  const float* Wp   = (const float*)d_in[2];
  const float* bp   = (const float*)d_in[3];
  const float* Wg   = (const float*)d_in[4];
  const float* bg   = (const float*)d_in[5];
  const float* lng  = (const float*)d_in[6];
  const float* lnb  = (const float*)d_in[7];
  const float* dq   = (const float*)d_in[8];
  char* ws = (char*)d_ws;

  constexpr size_t REG  = (size_t)NNODE*CC*2;                                   // 67,108,864
  constexpr size_t WTS  = 2u*131072;
  constexpr size_t GBLK = 524288u*2 + (size_t)NNODE*CAP*4 + (size_t)256*4096*4; // ~21.8 MB
  if (ws_size < 2*REG + WTS + GBLK) return;

  u16* x_hi = (u16*)(ws + 0);
  u16* xl   = (u16*)(ws + REG);
  char* wts  = ws + 2*REG;
  char* gblk = wts + WTS;

  u16* WpT_hi = (u16*)(wts);
  u16* WgT_hi = (u16*)(wts + 131072);
  int*   cur    = (int*)(gblk);
  float* dinv   = (float*)(gblk + 524288);
  int*   bucket = (int*)(gblk + 1048576);
  float* logits = (float*)(gblk + 1048576 + (size_t)NNODE*CAP*4);

  // weight transposes (tiny, hi only)
  transpose_split<<<dim3(4,4,1), 256, 0, stream>>>(Wp, WpT_hi, nullptr, 256, 256, 0, 0);
  transpose_split<<<dim3(4,4,1), 256, 0, stream>>>(Wg, WgT_hi, nullptr, 256, 256, 0, 0);

  // graph prep
  hipMemsetAsync(cur, 0, 524288, stream);
  fill_all <<<2048, 256, 0, stream>>>(edges, edges+EEDG, cur, bucket);
  calc_dinv<<<512,  256, 0, stream>>>(cur, dinv);

  // x = imgT @ Wp + bp   (transpose fused, img read once, 1-product)
  gemm_img<<<2048, 256, 0, stream>>>(img, WpT_hi, bp, x_hi);
  // xl = x @ Wg          (x read once, 1-product)
  gemm1p<<<2048, 256, 0, stream>>>(x_hi, WgT_hi, xl);

  float* outg = (float*)d_out;
  float* outa = (float*)d_out + (size_t)NNODE*CC;
  fused_agg<<<NNODE/8, 256, 0, stream>>>(xl, x_hi, cur, dinv, bucket,
                                         bg, lng, lnb, dq, outg, logits);
  softmax_rows<<<256, 256, 0, stream>>>(logits, outa);
}